// Round 4
// baseline (4952.893 us; speedup 1.0000x reference)
//
#include <hip/hip_runtime.h>
#include <math.h>

#define NN   50000      // nodes per type
#define NTOT 100000
#define FD   256        // hidden dim
#define EC   150000     // edges per edge type

static const size_t NF = (size_t)NN * FD;   // 12.8M floats

__device__ __forceinline__ float gelu_f(float x) {
  return 0.5f * x * (1.0f + erff(x * 0.7071067811865475f));
}
__device__ __forceinline__ unsigned short f2bf(float x) {   // RTN f32->bf16
  unsigned u = __float_as_uint(x);
  u += 0x7FFFu + ((u >> 16) & 1u);
  return (unsigned short)(u >> 16);
}
__device__ __forceinline__ float bf2f(unsigned short u) {
  return __uint_as_float((unsigned)u << 16);
}

// ---------------------------------------------------------------------------
// f32 GEMM, 128x128 tile, K=256 fixed, reg-staged double-buffered LDS,
// one barrier per K-step.
// MODE 0: multi-seg out (per 256-col segment), seg0 f32 + seg1/2 bf16
// MODE 3: multi-seg out, all segs bf16
// MODE 1: single f32 out + skip-gate epilogue (C may alias Xs)
// MODE 2: single f32 out + gelu epilogue
// ---------------------------------------------------------------------------
template<int GELU_A, int MODE>
__global__ __launch_bounds__(256) void gemm_k(
    const float* __restrict__ A, int lda,
    const float* __restrict__ B, int ldb,
    const float* __restrict__ bias,
    void* d0, void* d1, void* d2,
    const float* Xs, const float* __restrict__ skipp,
    int M, int N)
{
  __shared__ float As[2][16][128];
  __shared__ float Bs[2][16][132];
  const int tid = threadIdx.x;
  const int tx = tid & 15, ty = tid >> 4;
  const int arow = tid >> 1, acg = (tid & 1) * 8;
  const int br = tid >> 4, bc0 = (tid & 15) * 4;
  const int bm = blockIdx.y * 128, bn = blockIdx.x * 128;
  const bool avalid = (bm + arow) < M;
  const float* aptr = A + (size_t)(bm + arow) * lda + acg;
  const float* bptr = B + (size_t)br * ldb + bn;
  float acc[8][8] = {};
  float4 ra0 = make_float4(0.f,0.f,0.f,0.f), ra1 = make_float4(0.f,0.f,0.f,0.f);
  float4 rb0, rb1;

#define LOADT(K0) { \
    if (avalid) { ra0 = *(const float4*)(aptr + (K0)); ra1 = *(const float4*)(aptr + (K0) + 4); } \
    rb0 = *(const float4*)(bptr + (size_t)(K0) * ldb + bc0); \
    rb1 = *(const float4*)(bptr + (size_t)(K0) * ldb + bc0 + 64); }

#define STORET(BUF) { float4 a0 = ra0, a1 = ra1; \
    if (GELU_A) { a0.x=gelu_f(a0.x); a0.y=gelu_f(a0.y); a0.z=gelu_f(a0.z); a0.w=gelu_f(a0.w); \
                  a1.x=gelu_f(a1.x); a1.y=gelu_f(a1.y); a1.z=gelu_f(a1.z); a1.w=gelu_f(a1.w); } \
    As[BUF][acg+0][arow]=a0.x; As[BUF][acg+1][arow]=a0.y; \
    As[BUF][acg+2][arow]=a0.z; As[BUF][acg+3][arow]=a0.w; \
    As[BUF][acg+4][arow]=a1.x; As[BUF][acg+5][arow]=a1.y; \
    As[BUF][acg+6][arow]=a1.z; As[BUF][acg+7][arow]=a1.w; \
    *(float4*)&Bs[BUF][br][bc0] = rb0; *(float4*)&Bs[BUF][br][bc0+64] = rb1; }

#define COMPUTE(BUF) { \
    _Pragma("unroll") \
    for (int kk = 0; kk < 16; kk++) { \
      float4 a0 = *(const float4*)&As[BUF][kk][ty*4]; \
      float4 a1 = *(const float4*)&As[BUF][kk][64 + ty*4]; \
      float4 b0 = *(const float4*)&Bs[BUF][kk][tx*4]; \
      float4 b1 = *(const float4*)&Bs[BUF][kk][64 + tx*4]; \
      float av[8] = {a0.x,a0.y,a0.z,a0.w,a1.x,a1.y,a1.z,a1.w}; \
      float bv[8] = {b0.x,b0.y,b0.z,b0.w,b1.x,b1.y,b1.z,b1.w}; \
      _Pragma("unroll") for (int i = 0; i < 8; i++) \
        _Pragma("unroll") for (int j = 0; j < 8; j++) \
          acc[i][j] = fmaf(av[i], bv[j], acc[i][j]); } }

  LOADT(0); STORET(0);
  int cur = 0;
  for (int k0 = 16; k0 < 256; k0 += 16) {
    __syncthreads();
    LOADT(k0);
    COMPUTE(cur);
    STORET(cur ^ 1);
    cur ^= 1;
  }
  __syncthreads();
  COMPUTE(cur);
#undef LOADT
#undef STORET
#undef COMPUTE

  float sg = 0.f;
  if (MODE == 1) sg = 1.f / (1.f + expf(-skipp[0]));
  const int seg = bn >> 8;                 // uniform per block
  const int cb = (MODE == 0 || MODE == 3) ? (bn & 255) : bn;
  void* dst = d0;
  if (MODE == 0 || MODE == 3) dst = (seg == 0) ? d0 : ((seg == 1) ? d1 : d2);
  #pragma unroll
  for (int i = 0; i < 8; i++) {
    int rr = (i < 4) ? (ty*4 + i) : (64 + ty*4 + (i - 4));
    int r = bm + rr;
    if (r >= M) continue;
    #pragma unroll
    for (int half = 0; half < 2; half++) {
      int gc = bn + half*64 + tx*4;        // column into bias (packed B space)
      int lc = cb + half*64 + tx*4;        // column within 256-wide dst
      float v[4];
      #pragma unroll
      for (int j = 0; j < 4; j++) {
        float x = acc[i][half*4 + j] + bias[gc + j];
        if (MODE == 2) x = gelu_f(x);
        v[j] = x;
      }
      if (MODE == 1) {
        float4 xs = *(const float4*)&Xs[(size_t)r * FD + lc];
        v[0] = sg*v[0] + (1.f-sg)*xs.x;
        v[1] = sg*v[1] + (1.f-sg)*xs.y;
        v[2] = sg*v[2] + (1.f-sg)*xs.z;
        v[3] = sg*v[3] + (1.f-sg)*xs.w;
      }
      const bool f32out = (MODE == 1 || MODE == 2 || (MODE == 0 && seg == 0));
      if (f32out) {
        *(float4*)&((float*)dst)[(size_t)r * FD + lc] = make_float4(v[0], v[1], v[2], v[3]);
      } else {
        ushort4 o;
        o.x = f2bf(v[0]); o.y = f2bf(v[1]); o.z = f2bf(v[2]); o.w = f2bf(v[3]);
        *(ushort4*)&((unsigned short*)dst)[(size_t)r * FD + lc] = o;
      }
    }
  }
}

// ---------------------------------------------------------------------------
// Combined relation weights written straight into the packed wide-B matrices:
// Bo1 = [KE0|VE0] (ldb 512), Bv = [Q_var|KE1|VE1] (768), Bo3 = [Q_op|KE2|VE2] (768)
// prel/sqrt(D) folded into k-side. grid (6,8), block 256.
// ---------------------------------------------------------------------------
__global__ __launch_bounds__(256) void wcomb_kernel(
    const float* __restrict__ Wkqv, const float* __restrict__ bkqv,
    const float* __restrict__ Wkrel, const float* __restrict__ Wvrel,
    const float* __restrict__ prel,
    float* __restrict__ Bo1, float* __restrict__ Bv, float* __restrict__ Bo3,
    float* __restrict__ bias_o1, float* __restrict__ bias_v, float* __restrict__ bias_o3)
{
  const int z = blockIdx.x, et = z >> 1, kv = z & 1;
  const int h = blockIdx.y;
  const int st = (et == 1) ? 1 : 0;
  const int cbase = (kv ? 512 : 0) + h * 32;   // K block cols [0,256), V block [512,768)
  const float scale = kv ? 1.0f : (prel[et*8 + h] * 0.1767766952966369f);
  float* Bdst; int ldbz, ofs; float* bdst;
  if (z == 0)      { Bdst = Bo1; ldbz = 512; ofs = 0;   bdst = bias_o1; }
  else if (z == 1) { Bdst = Bo1; ldbz = 512; ofs = 256; bdst = bias_o1; }
  else if (z == 2) { Bdst = Bv;  ldbz = 768; ofs = 256; bdst = bias_v;  }
  else if (z == 3) { Bdst = Bv;  ldbz = 768; ofs = 512; bdst = bias_v;  }
  else if (z == 4) { Bdst = Bo3; ldbz = 768; ofs = 256; bdst = bias_o3; }
  else             { Bdst = Bo3; ldbz = 768; ofs = 512; bdst = bias_o3; }
  __shared__ float Wr[32][32];
  const int tid = threadIdx.x;
  {
    const float* wr = (kv ? Wvrel : Wkrel) + ((size_t)(h*3 + et)) * 1024;
    for (int i = tid; i < 1024; i += 256) Wr[i >> 5][i & 31] = wr[i];
  }
  __syncthreads();
  const float* w1 = Wkqv + (size_t)st * 196608 + (size_t)tid * 768 + cbase;
  float acc[32] = {};
  for (int d = 0; d < 32; d++) {
    float v = w1[d];
    #pragma unroll
    for (int j = 0; j < 32; j++) acc[j] = fmaf(v, Wr[d][j], acc[j]);
  }
  float* outp = Bdst + (size_t)tid * ldbz + ofs + h * 32;
  for (int j = 0; j < 32; j++) outp[j] = acc[j] * scale;
  if (tid < 32) {
    const float* bk = bkqv + st * 768 + cbase;
    float a = 0.f;
    for (int d = 0; d < 32; d++) a = fmaf(bk[d], Wr[d][tid], a);
    bdst[ofs + h * 32 + tid] = a * scale;
  }
}

// Q weight/bias copy into seg0 of Bv / Bo3. grid (256, 2), block 256.
__global__ __launch_bounds__(256) void qpack_kernel(
    const float* __restrict__ Wkqv, const float* __restrict__ bkqv,
    float* __restrict__ Bo3, float* __restrict__ Bv,
    float* __restrict__ bias_o3, float* __restrict__ bias_v)
{
  const int r = blockIdx.x, t = blockIdx.y, c = threadIdx.x;
  float w = Wkqv[(size_t)t * 196608 + (size_t)r * 768 + 256 + c];
  (t ? Bv : Bo3)[(size_t)r * 768 + c] = w;
  if (r == 0) (t ? bias_v : bias_o3)[c] = bkqv[t * 768 + 256 + c];
}

// ---------------------------------------------------------------------------
// Union-CSR attention: one wave per dst node, online softmax over all
// in-edges, agg written over the Q row (each row owned by one wave).
// ---------------------------------------------------------------------------
__global__ __launch_bounds__(256) void attn_union(
    float* qagg,                                  // [NN,256]: Q in, agg out
    const unsigned short* __restrict__ KEu,       // [2NN,256] bf16
    const unsigned short* __restrict__ VEu,       // [2NN,256] bf16
    const int* __restrict__ indptr, const int* __restrict__ adj)
{
  const int wid = (int)(((size_t)blockIdx.x * 256 + threadIdx.x) >> 6);
  if (wid >= NN) return;
  const int lane = threadIdx.x & 63;
  const int off = lane * 4;
  const float4 q4 = *(const float4*)(qagg + (size_t)wid * FD + off);
  float m = -INFINITY, s = 0.f, ax = 0.f, ay = 0.f, az = 0.f, aw = 0.f;
  const int beg = indptr[wid], end = indptr[wid + 1];
  for (int i = beg; i < end; i++) {
    const int src = adj[i];     // global src id in [0, 2*NN)
    ushort4 ku = *(const ushort4*)(KEu + (size_t)src * FD + off);
    float d = q4.x*bf2f(ku.x) + q4.y*bf2f(ku.y) + q4.z*bf2f(ku.z) + q4.w*bf2f(ku.w);
    d += __shfl_xor(d, 1); d += __shfl_xor(d, 2); d += __shfl_xor(d, 4);
    float mn = fmaxf(m, d);
    float sc = expf(m - mn);    // m=-inf on first edge -> 0
    float w  = expf(d - mn);
    s = s * sc + w;
    ushort4 vu = *(const ushort4*)(VEu + (size_t)src * FD + off);
    ax = ax*sc + w*bf2f(vu.x); ay = ay*sc + w*bf2f(vu.y);
    az = az*sc + w*bf2f(vu.z); aw = aw*sc + w*bf2f(vu.w);
    m = mn;
  }
  const float inv = 1.f / (s + 1e-16f);
  *(float4*)(qagg + (size_t)wid * FD + off) = make_float4(ax*inv, ay*inv, az*inv, aw*inv);
}

// ---------------------------------------------------------------------------
__global__ __launch_bounds__(256) void ln_gelu_kernel(
    float* __restrict__ x, const float* __restrict__ g, const float* __restrict__ b)
{
  const int wid = (int)(((size_t)blockIdx.x * 256 + threadIdx.x) >> 6);
  if (wid >= NTOT) return;
  const int lane = threadIdx.x & 63;
  const int t = (wid >= NN) ? 1 : 0;   // rows [0,NN)=op, [NN,2NN)=var
  float4 v = *(float4*)(x + (size_t)wid * FD + lane*4);
  float sum = v.x + v.y + v.z + v.w;
  #pragma unroll
  for (int o = 1; o < 64; o <<= 1) sum += __shfl_xor(sum, o);
  float mu = sum * (1.f/256.f);
  float dx = v.x-mu, dy = v.y-mu, dz = v.z-mu, dw = v.w-mu;
  float vs = dx*dx + dy*dy + dz*dz + dw*dw;
  #pragma unroll
  for (int o = 1; o < 64; o <<= 1) vs += __shfl_xor(vs, o);
  float var = vs * (1.f/256.f);
  float rs = 1.f / sqrtf(var + 1e-5f);
  int c = lane*4;
  float4 gv = *(const float4*)(g + t*FD + c);
  float4 bv = *(const float4*)(b + t*FD + c);
  float y0 = dx*rs*gv.x + bv.x, y1 = dy*rs*gv.y + bv.y;
  float y2 = dz*rs*gv.z + bv.z, y3 = dw*rs*gv.w + bv.w;
  float4 o4 = make_float4(gelu_f(y0), gelu_f(y1), gelu_f(y2), gelu_f(y3));
  *(float4*)(x + (size_t)wid * FD + c) = o4;
}

__global__ __launch_bounds__(256) void gelu_kernel(float* __restrict__ x, size_t n4)
{
  size_t i = ((size_t)blockIdx.x * 256 + threadIdx.x);
  if (i >= n4) return;
  float4 v = *(float4*)(x + i*4);
  v.x = gelu_f(v.x); v.y = gelu_f(v.y); v.z = gelu_f(v.z); v.w = gelu_f(v.w);
  *(float4*)(x + i*4) = v;
}

// ---------------------------------------------------------------------------
// CSR build: var-dst CSR (from e0) and op-dst union CSR (from e1+e2).
// adj stores GLOBAL src id: op src = id, var src = NN+id.
// ---------------------------------------------------------------------------
__global__ __launch_bounds__(256) void count_v(const int* __restrict__ e0,
                                               int* __restrict__ degv) {
  int i = blockIdx.x * 256 + threadIdx.x;
  if (i >= EC) return;
  atomicAdd(&degv[e0[EC + i]], 1);
}
__global__ __launch_bounds__(256) void count_o(const int* __restrict__ e1,
                                               const int* __restrict__ e2,
                                               int* __restrict__ dego) {
  int i = blockIdx.x * 256 + threadIdx.x;
  if (i >= 2*EC) return;
  int dst = (i < EC) ? e1[EC + i] : e2[EC + (i - EC)];
  atomicAdd(&dego[dst], 1);
}

__global__ __launch_bounds__(1024) void scan_n(
    const int* __restrict__ deg, int* __restrict__ indptr,
    int* __restrict__ cursor, int n)
{
  __shared__ int ts[1024];
  const int tid = threadIdx.x;
  const int per = (n + 1023) / 1024;
  int s0 = tid * per, s1 = s0 + per; if (s1 > n) s1 = n; if (s0 > n) s0 = n;
  int loc = 0;
  for (int i = s0; i < s1; i++) loc += deg[i];
  ts[tid] = loc;
  __syncthreads();
  for (int off = 1; off < 1024; off <<= 1) {
    int v = (tid >= off) ? ts[tid - off] : 0;
    __syncthreads();
    ts[tid] += v;
    __syncthreads();
  }
  int base = (tid == 0) ? 0 : ts[tid - 1];
  for (int i = s0; i < s1; i++) {
    indptr[i] = base; cursor[i] = base; base += deg[i];
  }
  if (tid == 0) indptr[n] = ts[1023];
}

__global__ __launch_bounds__(256) void scat_v(const int* __restrict__ e0,
                                              int* __restrict__ cv,
                                              int* __restrict__ adjv) {
  int i = blockIdx.x * 256 + threadIdx.x;
  if (i >= EC) return;
  int pos = atomicAdd(&cv[e0[EC + i]], 1);
  adjv[pos] = e0[i];                      // src is op type -> global id
}
__global__ __launch_bounds__(256) void scat_o(const int* __restrict__ e1,
                                              const int* __restrict__ e2,
                                              int* __restrict__ co,
                                              int* __restrict__ adjo) {
  int i = blockIdx.x * 256 + threadIdx.x;
  if (i >= 2*EC) return;
  int dst, srcg;
  if (i < EC) { dst = e1[EC + i]; srcg = NN + e1[i]; }            // et1: var src
  else        { int j = i - EC; dst = e2[EC + j]; srcg = e2[j]; } // et2: op src
  int pos = atomicAdd(&co[dst], 1);
  adjo[pos] = srcg;
}

// ---------------------------------------------------------------------------
__global__ __launch_bounds__(256) void colmean_kernel(
    const float* __restrict__ gmat, double* __restrict__ outp, int n)
{
  const int c = threadIdx.x;
  const int r0 = blockIdx.x * 256;
  int rend = r0 + 256; if (rend > n) rend = n;
  double sum = 0.0;
  for (int r = r0; r < rend; r++) sum += (double)gmat[(size_t)r * FD + c];
  atomicAdd(&outp[c], sum);
}

__global__ __launch_bounds__(256) void head_kernel(
    const double* __restrict__ meand,
    const float* __restrict__ Wagg2, const float* __restrict__ bagg2,
    const float* __restrict__ Wo, const float* __restrict__ bo,
    float* __restrict__ outp)
{
  __shared__ float mv[256];
  __shared__ float h2[128];
  const int tid = threadIdx.x;
  mv[tid] = (float)(meand[tid] * (1.0 / (double)NTOT));
  __syncthreads();
  if (tid < 128) {
    float acc = bagg2[tid];
    for (int k = 0; k < 256; k++) acc = fmaf(mv[k], Wagg2[k*128 + tid], acc);
    h2[tid] = gelu_f(acc);
  }
  __syncthreads();
  if (tid < 16) {
    float acc = bo[tid];
    for (int k = 0; k < 128; k++) acc = fmaf(h2[k], Wo[k*16 + tid], acc);
    if (isnan(acc)) acc = 0.f;
    else if (isinf(acc)) acc = (acc > 0.f) ? 3.4028234663852886e38f : -3.4028234663852886e38f;
    outp[tid] = acc;
  }
}

__global__ void fill_kernel(float* p, int n, float v) {
  int i = blockIdx.x * 64 + threadIdx.x;
  if (i < n) p[i] = v;
}

// ---------------------------------------------------------------------------
extern "C" void kernel_launch(void* const* d_in, const int* in_sizes, int n_in,
                              void* d_out, int out_size, void* d_ws, size_t ws_size,
                              hipStream_t stream)
{
  const float* x_op_in  = (const float*)d_in[0];
  const float* x_var_in = (const float*)d_in[1];
  struct LayerP { const float *Wkqv,*bkqv,*Wkrel,*Wvrel,*prel,*Wout,*bout,*skip; };
  LayerP L[3];
  for (int i = 0; i < 3; i++) {
    int b = 2 + i*8;
    L[i].Wkqv  = (const float*)d_in[b+0];
    L[i].bkqv  = (const float*)d_in[b+1];
    L[i].Wkrel = (const float*)d_in[b+2];
    L[i].Wvrel = (const float*)d_in[b+3];
    L[i].prel  = (const float*)d_in[b+4];
    L[i].Wout  = (const float*)d_in[b+5];
    L[i].bout  = (const float*)d_in[b+6];
    L[i].skip  = (const float*)d_in[b+7];
  }
  const float* ln_g  = (const float*)d_in[26];
  const float* ln_b  = (const float*)d_in[27];
  const float* Wagg1 = (const float*)d_in[28];
  const float* bagg1 = (const float*)d_in[29];
  const float* Wagg2 = (const float*)d_in[30];
  const float* bagg2 = (const float*)d_in[31];
  const float* Wo    = (const float*)d_in[32];
  const float* bo    = (const float*)d_in[33];
  const int* e0 = (const int*)d_in[34];   // op -> var
  const int* e1 = (const int*)d_in[35];   // var -> op
  const int* e2 = (const int*)d_in[36];   // op -> op

  // ---- workspace layout (~249 MiB) ----
  float* X    = (float*)d_ws;               // 2NF: op rows then var rows
  float* Xop  = X;
  float* Xvar = X + NF;
  float* Qb   = X + 2*NF;                   // NF: Q / agg (aliased)
  unsigned short* KEu = (unsigned short*)(X + 3*NF);  // [2NN,256] bf16
  unsigned short* VEu = (unsigned short*)(X + 4*NF);  // [2NN,256] bf16
  float* Bo1  = X + 5*NF;                   // [256,512]
  float* Bv   = Bo1 + 131072;               // [256,768]
  float* Bo3  = Bv + 196608;                // [256,768]
  float* b_o1 = Bo3 + 196608;               // 512
  float* b_v  = b_o1 + 512;                 // 768
  float* b_o3 = b_v + 768;                  // 768
  double* meand = (double*)(b_o3 + 768);    // 256 doubles
  int* ipv  = (int*)(meand + 256);          // NN+1
  int* ipo  = ipv + (NN + 1);               // NN+1
  int* cv   = ipo + (NN + 1);               // NN
  int* co   = cv + NN;                      // NN
  int* degv = co + NN;                      // NN
  int* dego = degv + NN;                    // NN
  int* adjv = dego + NN;                    // EC
  int* adjo = adjv + EC;                    // 2*EC
  size_t need = (size_t)((char*)(adjo + 2*EC) - (char*)d_ws);
  if (ws_size < need) {   // sentinel encodes ws_size in MiB*1000
    float v = (float)(ws_size >> 20) * 1000.0f;
    fill_kernel<<<dim3((out_size + 63)/64), 64, 0, stream>>>((float*)d_out, out_size, v);
    return;
  }

  // ---- CSR build (edges constant across layers) ----
  hipMemsetAsync(degv, 0, 2*NN*sizeof(int), stream);   // degv+dego contiguous
  hipMemsetAsync(meand, 0, 256*sizeof(double), stream);
  count_v<<<dim3((EC + 255)/256), 256, 0, stream>>>(e0, degv);
  count_o<<<dim3((2*EC + 255)/256), 256, 0, stream>>>(e1, e2, dego);
  scan_n<<<dim3(1), 1024, 0, stream>>>(degv, ipv, cv, NN);
  scan_n<<<dim3(1), 1024, 0, stream>>>(dego, ipo, co, NN);
  scat_v<<<dim3((EC + 255)/256), 256, 0, stream>>>(e0, cv, adjv);
  scat_o<<<dim3((2*EC + 255)/256), 256, 0, stream>>>(e1, e2, co, adjo);

  const dim3 gw4(4, 391), gw6(6, 391), gw2(2, 391);
  const dim3 ga((NN*64 + 255)/256);

  for (int layer = 0; layer < 3; layer++) {
    const LayerP& P = L[layer];
    const float* xo = layer ? Xop  : x_op_in;
    const float* xv = layer ? Xvar : x_var_in;

    wcomb_kernel<<<dim3(6, 8), 256, 0, stream>>>(P.Wkqv, P.bkqv, P.Wkrel, P.Wvrel,
                                                 P.prel, Bo1, Bv, Bo3, b_o1, b_v, b_o3);
    qpack_kernel<<<dim3(256, 2), 256, 0, stream>>>(P.Wkqv, P.bkqv, Bo3, Bv, b_o3, b_v);

    // ---- VAR-dst phase (et0: op -> var) ----
    gemm_k<0,3><<<gw4, 256, 0, stream>>>(             // [KE0|VE0] from x_op
        xo, FD, Bo1, 512, b_o1, KEu, VEu, nullptr, nullptr, nullptr, NN, 512);
    gemm_k<0,0><<<gw6, 256, 0, stream>>>(             // [Q_var|KE1|VE1] from x_var
        xv, FD, Bv, 768, b_v, Qb, KEu + NF, VEu + NF, nullptr, nullptr, NN, 768);
    attn_union<<<ga, 256, 0, stream>>>(Qb, KEu, VEu, ipv, adjv);
    gemm_k<1,1><<<gw2, 256, 0, stream>>>(             // Wout var (in-place skip)
        Qb, FD, P.Wout + 65536, 256, P.bout + 256, Xvar, nullptr, nullptr,
        xv, P.skip + 1, NN, 256);

    // ---- OP-dst phase (et1: var->op rows [NN,2NN); et2: op->op rows [0,NN)) ----
    gemm_k<0,0><<<gw6, 256, 0, stream>>>(             // [Q_op|KE2|VE2] from x_op
        xo, FD, Bo3, 768, b_o3, Qb, KEu, VEu, nullptr, nullptr, NN, 768);
    attn_union<<<ga, 256, 0, stream>>>(Qb, KEu, VEu, ipo, adjo);
    gemm_k<1,1><<<gw2, 256, 0, stream>>>(             // Wout op (in-place skip)
        Qb, FD, P.Wout, 256, P.bout, Xop, nullptr, nullptr,
        xo, P.skip + 0, NN, 256);

    // ---- inter-layer elementwise on contiguous 2NF ----
    if (layer == 0)
      ln_gelu_kernel<<<dim3((NTOT*64 + 255)/256), 256, 0, stream>>>(X, ln_g, ln_b);
    else
      gelu_kernel<<<dim3((int)(2*NF/4 + 255)/256), 256, 0, stream>>>(X, 2*NF/4);
  }

  // ---- final head: gelu(h @ Wagg1 + b) -> column mean (f64) -> MLP ----
  gemm_k<0,2><<<gw2, 256, 0, stream>>>(
      Xop, FD, Wagg1, 256, bagg1, Qb, nullptr, nullptr, nullptr, nullptr, NN, 256);
  colmean_kernel<<<dim3((NN + 255)/256), 256, 0, stream>>>(Qb, meand, NN);
  gemm_k<0,2><<<gw2, 256, 0, stream>>>(
      Xvar, FD, Wagg1 + 65536, 256, bagg1 + 256, Qb, nullptr, nullptr, nullptr, nullptr, NN, 256);
  colmean_kernel<<<dim3((NN + 255)/256), 256, 0, stream>>>(Qb, meand, NN);
  head_kernel<<<dim3(1), 256, 0, stream>>>(meand, Wagg2, bagg2, Wo, bo, (float*)d_out);
}

// Round 5
// 2304.120 us; speedup vs baseline: 2.1496x; 2.1496x over previous
//
#include <hip/hip_runtime.h>
#include <math.h>

#define NN   50000      // nodes per type
#define NTOT 100000
#define FD   256        // hidden dim
#define EC   150000     // edges per edge type

static const size_t NF = (size_t)NN * FD;   // 12.8M (= NN*256)

typedef __attribute__((ext_vector_type(8))) short bf16x8;
typedef __attribute__((ext_vector_type(4))) float f32x4;

__device__ __forceinline__ float gelu_f(float x) {
  return 0.5f * x * (1.0f + erff(x * 0.7071067811865475f));
}
__device__ __forceinline__ unsigned short f2bf(float x) {   // RTN f32->bf16
  unsigned u = __float_as_uint(x);
  u += 0x7FFFu + ((u >> 16) & 1u);
  return (unsigned short)(u >> 16);
}
__device__ __forceinline__ float bf2f(unsigned short u) {
  return __uint_as_float((unsigned)u << 16);
}

// ---------------------------------------------------------------------------
// bf16 MFMA GEMM. A: [M,256] bf16 row-major. Bt: [N,256] bf16 (W^T).
// C = A@B + bias, f32 accum. 128x128 tile, BK=64, 4 waves x (64x64).
// LDS granule-swizzled (g ^= row&7) -> conflict-free-ish ds_read_b128.
// MODE 0: multiseg N=768: seg0->d0 f32, seg1->d1 bf16, seg2->d2 bf16
// MODE 3: multiseg N=512: seg0->d0 bf16, seg1->d1 bf16
// MODE 1: N=256, skip epilogue: out bf16 d0 (in-place over Xs ok);
//         Xs f32 (XSF=0) or bf16 (XSF=1)
// MODE 2: N=256, gelu epilogue -> f32 d0
// ---------------------------------------------------------------------------
template<int MODE, int XSF>
__global__ __launch_bounds__(256) void gemm_bf(
    const unsigned short* __restrict__ A,
    const unsigned short* __restrict__ Bt,
    const float* __restrict__ bias,
    void* d0, void* d1, void* d2,
    const void* Xs, const float* __restrict__ skipp, int M)
{
  __shared__ unsigned short As[128 * 64];
  __shared__ unsigned short Bs[128 * 64];
  const int tid = threadIdx.x;
  const int lane = tid & 63;
  const int wave = tid >> 6;
  const int wr = wave >> 1, wc = wave & 1;
  const int l15 = lane & 15, lq = lane >> 4;
  const int bm = blockIdx.y * 128, bn = blockIdx.x * 128;
  // staging: thread covers granules (sr, sg0..sg0+3); granule = 8 bf16 = 16B
  const int sr = tid >> 1, sg0 = (tid & 1) * 4;
  const bool av = (bm + sr) < M;
  const unsigned short* ag = A  + (size_t)(bm + sr) * 256 + sg0 * 8;
  const unsigned short* bg = Bt + (size_t)(bn + sr) * 256 + sg0 * 8;

  f32x4 acc[4][4] = {};
  uint4 ra[4], rb[4];

#define LOADT(KT) { \
    const unsigned short* ap = ag + (KT) * 64; \
    const unsigned short* bp = bg + (KT) * 64; \
    if (av) { ra[0] = *(const uint4*)(ap);      ra[1] = *(const uint4*)(ap + 8); \
              ra[2] = *(const uint4*)(ap + 16); ra[3] = *(const uint4*)(ap + 24); } \
    else    { ra[0] = ra[1] = ra[2] = ra[3] = make_uint4(0,0,0,0); } \
    rb[0] = *(const uint4*)(bp);      rb[1] = *(const uint4*)(bp + 8); \
    rb[2] = *(const uint4*)(bp + 16); rb[3] = *(const uint4*)(bp + 24); }

  LOADT(0);
  for (int kt = 0; kt < 4; kt++) {
    __syncthreads();
    #pragma unroll
    for (int i = 0; i < 4; i++) {
      const int g = sg0 + i;
      *(uint4*)&As[sr * 64 + ((g ^ (sr & 7)) << 3)] = ra[i];
      *(uint4*)&Bs[sr * 64 + ((g ^ (sr & 7)) << 3)] = rb[i];
    }
    __syncthreads();
    if (kt < 3) LOADT(kt + 1);          // issue next-tile loads early (T14)
    #pragma unroll
    for (int ks = 0; ks < 2; ks++) {
      bf16x8 af[4], bv[4];
      const int g = ks * 4 + lq;
      #pragma unroll
      for (int mi = 0; mi < 4; mi++) {
        const int r = wr * 64 + mi * 16 + l15;
        af[mi] = *(const bf16x8*)&As[r * 64 + ((g ^ (r & 7)) << 3)];
      }
      #pragma unroll
      for (int ni = 0; ni < 4; ni++) {
        const int c = wc * 64 + ni * 16 + l15;
        bv[ni] = *(const bf16x8*)&Bs[c * 64 + ((g ^ (c & 7)) << 3)];
      }
      #pragma unroll
      for (int mi = 0; mi < 4; mi++)
        #pragma unroll
        for (int ni = 0; ni < 4; ni++)
          acc[mi][ni] = __builtin_amdgcn_mfma_f32_16x16x32_bf16(
              af[mi], bv[ni], acc[mi][ni], 0, 0, 0);
    }
  }
#undef LOADT

  const int seg = (MODE == 0 || MODE == 3) ? (bn >> 8) : 0;
  float sg = 0.f;
  if (MODE == 1) sg = 1.f / (1.f + expf(-skipp[0]));
  #pragma unroll
  for (int mi = 0; mi < 4; mi++) {
    #pragma unroll
    for (int ni = 0; ni < 4; ni++) {
      const int cp = bn + wc * 64 + ni * 16 + l15;     // packed col (bias idx)
      const float bc_ = bias[cp];
      const int co = (MODE == 0 || MODE == 3) ? (cp & 255) : cp;
      #pragma unroll
      for (int j = 0; j < 4; j++) {
        const int r = bm + wr * 64 + mi * 16 + lq * 4 + j;
        if (r >= M) continue;
        float v = acc[mi][ni][j] + bc_;
        const size_t oidx = (size_t)r * 256 + co;
        if (MODE == 2) {
          ((float*)d0)[oidx] = gelu_f(v);
        } else if (MODE == 1) {
          const float xs = XSF ? bf2f(((const unsigned short*)Xs)[oidx])
                               : ((const float*)Xs)[oidx];
          ((unsigned short*)d0)[oidx] = f2bf(sg * v + (1.f - sg) * xs);
        } else if (MODE == 0) {
          if (seg == 0) ((float*)d0)[oidx] = v;
          else ((unsigned short*)(seg == 1 ? d1 : d2))[oidx] = f2bf(v);
        } else {  // MODE 3
          ((unsigned short*)(seg == 0 ? d0 : d1))[oidx] = f2bf(v);
        }
      }
    }
  }
}

// ---------------------------------------------------------------------------
// Combined relation weights -> TRANSPOSED bf16 packed-B matrices:
// Bo1t rows[0,512): [KE0|VE0]; Bvt rows[0,768): [Q_var|KE1|VE1] (Q by qpack);
// Bo3t: [Q_op|KE2|VE2]. Row = packed output col, col = k. prel/sqrtD on k-side.
// ---------------------------------------------------------------------------
__global__ __launch_bounds__(256) void wcomb_kernel(
    const float* __restrict__ Wkqv, const float* __restrict__ bkqv,
    const float* __restrict__ Wkrel, const float* __restrict__ Wvrel,
    const float* __restrict__ prel,
    unsigned short* __restrict__ Bo1t, unsigned short* __restrict__ Bvt,
    unsigned short* __restrict__ Bo3t,
    float* __restrict__ bias_o1, float* __restrict__ bias_v, float* __restrict__ bias_o3)
{
  const int z = blockIdx.x, et = z >> 1, kv = z & 1;
  const int h = blockIdx.y;
  const int st = (et == 1) ? 1 : 0;
  const int cbase = (kv ? 512 : 0) + h * 32;
  const float scale = kv ? 1.0f : (prel[et*8 + h] * 0.1767766952966369f);
  unsigned short* Bdst; int ofs; float* bdst;
  if (z == 0)      { Bdst = Bo1t; ofs = 0;   bdst = bias_o1; }
  else if (z == 1) { Bdst = Bo1t; ofs = 256; bdst = bias_o1; }
  else if (z == 2) { Bdst = Bvt;  ofs = 256; bdst = bias_v;  }
  else if (z == 3) { Bdst = Bvt;  ofs = 512; bdst = bias_v;  }
  else if (z == 4) { Bdst = Bo3t; ofs = 256; bdst = bias_o3; }
  else             { Bdst = Bo3t; ofs = 512; bdst = bias_o3; }
  __shared__ float Wr[32][32];
  const int tid = threadIdx.x;
  {
    const float* wr = (kv ? Wvrel : Wkrel) + ((size_t)(h*3 + et)) * 1024;
    for (int i = tid; i < 1024; i += 256) Wr[i >> 5][i & 31] = wr[i];
  }
  __syncthreads();
  const float* w1 = Wkqv + (size_t)st * 196608 + (size_t)tid * 768 + cbase;
  float acc[32] = {};
  for (int d = 0; d < 32; d++) {
    float v = w1[d];
    #pragma unroll
    for (int j = 0; j < 32; j++) acc[j] = fmaf(v, Wr[d][j], acc[j]);
  }
  for (int j = 0; j < 32; j++)
    Bdst[(size_t)(ofs + h * 32 + j) * 256 + tid] = f2bf(acc[j] * scale);
  if (tid < 32) {
    const float* bk = bkqv + st * 768 + cbase;
    float a = 0.f;
    for (int d = 0; d < 32; d++) a = fmaf(bk[d], Wr[d][tid], a);
    bdst[ofs + h * 32 + tid] = a * scale;
  }
}

// Q weights -> transposed bf16 seg0 of Bvt / Bo3t. grid (256, 2), block 256.
__global__ __launch_bounds__(256) void qpack_kernel(
    const float* __restrict__ Wkqv, const float* __restrict__ bkqv,
    unsigned short* __restrict__ Bo3t, unsigned short* __restrict__ Bvt,
    float* __restrict__ bias_o3, float* __restrict__ bias_v)
{
  const int r = blockIdx.x, t = blockIdx.y, c = threadIdx.x;
  float w = Wkqv[(size_t)t * 196608 + (size_t)r * 768 + 256 + c];
  (t ? Bvt : Bo3t)[(size_t)c * 256 + r] = f2bf(w);
  if (r == 0) (t ? bias_v : bias_o3)[c] = bkqv[t * 768 + 256 + c];
}

// generic [256,256] f32 -> transposed bf16
__global__ __launch_bounds__(256) void wcvt_kernel(
    const float* __restrict__ src, unsigned short* __restrict__ dst)
{
  const int r = blockIdx.x, c = threadIdx.x;
  dst[(size_t)c * 256 + r] = f2bf(src[(size_t)r * 256 + c]);
}

// ---------------------------------------------------------------------------
// Union-CSR attention: one wave per dst node, online softmax over all
// in-edges; epilogue applies gelu and writes bf16 aggb.
// ---------------------------------------------------------------------------
__global__ __launch_bounds__(256) void attn_union(
    const float* __restrict__ qb,                 // [NN,256] f32
    const unsigned short* __restrict__ KEu,       // [2NN,256] bf16
    const unsigned short* __restrict__ VEu,       // [2NN,256] bf16
    const int* __restrict__ indptr, const int* __restrict__ adj,
    unsigned short* __restrict__ aggb)            // [NN,256] bf16, gelu'd
{
  const int wid = (int)(((size_t)blockIdx.x * 256 + threadIdx.x) >> 6);
  if (wid >= NN) return;
  const int lane = threadIdx.x & 63;
  const int off = lane * 4;
  const float4 q4 = *(const float4*)(qb + (size_t)wid * FD + off);
  float m = -INFINITY, s = 0.f, ax = 0.f, ay = 0.f, az = 0.f, aw = 0.f;
  const int beg = indptr[wid], end = indptr[wid + 1];
  for (int i = beg; i < end; i++) {
    const int src = adj[i];     // global src id in [0, 2*NN)
    ushort4 ku = *(const ushort4*)(KEu + (size_t)src * FD + off);
    float d = q4.x*bf2f(ku.x) + q4.y*bf2f(ku.y) + q4.z*bf2f(ku.z) + q4.w*bf2f(ku.w);
    d += __shfl_xor(d, 1); d += __shfl_xor(d, 2); d += __shfl_xor(d, 4);
    float mn = fmaxf(m, d);
    float sc = expf(m - mn);    // m=-inf on first edge -> 0
    float w  = expf(d - mn);
    s = s * sc + w;
    ushort4 vu = *(const ushort4*)(VEu + (size_t)src * FD + off);
    ax = ax*sc + w*bf2f(vu.x); ay = ay*sc + w*bf2f(vu.y);
    az = az*sc + w*bf2f(vu.z); aw = aw*sc + w*bf2f(vu.w);
    m = mn;
  }
  const float inv = 1.f / (s + 1e-16f);
  ushort4 o;
  o.x = f2bf(gelu_f(ax * inv)); o.y = f2bf(gelu_f(ay * inv));
  o.z = f2bf(gelu_f(az * inv)); o.w = f2bf(gelu_f(aw * inv));
  *(ushort4*)(aggb + (size_t)wid * FD + off) = o;
}

// ---------------------------------------------------------------------------
__global__ __launch_bounds__(256) void ln_gelu_kernel(
    unsigned short* __restrict__ x, const float* __restrict__ g,
    const float* __restrict__ b)
{
  const int wid = (int)(((size_t)blockIdx.x * 256 + threadIdx.x) >> 6);
  if (wid >= NTOT) return;
  const int lane = threadIdx.x & 63;
  const int t = (wid >= NN) ? 1 : 0;   // rows [0,NN)=op, [NN,2NN)=var
  ushort4 u = *(ushort4*)(x + (size_t)wid * FD + lane*4);
  float vx = bf2f(u.x), vy = bf2f(u.y), vz = bf2f(u.z), vw = bf2f(u.w);
  float sum = vx + vy + vz + vw;
  #pragma unroll
  for (int o = 1; o < 64; o <<= 1) sum += __shfl_xor(sum, o);
  float mu = sum * (1.f/256.f);
  float dx = vx-mu, dy = vy-mu, dz = vz-mu, dw = vw-mu;
  float vs = dx*dx + dy*dy + dz*dz + dw*dw;
  #pragma unroll
  for (int o = 1; o < 64; o <<= 1) vs += __shfl_xor(vs, o);
  float var = vs * (1.f/256.f);
  float rs = 1.f / sqrtf(var + 1e-5f);
  int c = lane*4;
  float4 gv = *(const float4*)(g + t*FD + c);
  float4 bv = *(const float4*)(b + t*FD + c);
  ushort4 o4;
  o4.x = f2bf(gelu_f(dx*rs*gv.x + bv.x));
  o4.y = f2bf(gelu_f(dy*rs*gv.y + bv.y));
  o4.z = f2bf(gelu_f(dz*rs*gv.z + bv.z));
  o4.w = f2bf(gelu_f(dw*rs*gv.w + bv.w));
  *(ushort4*)(x + (size_t)wid * FD + c) = o4;
}

__global__ __launch_bounds__(256) void gelu_bf_kernel(
    unsigned short* __restrict__ x, size_t n4)
{
  size_t i = ((size_t)blockIdx.x * 256 + threadIdx.x);
  if (i >= n4) return;
  ushort4 u = ((ushort4*)x)[i];
  u.x = f2bf(gelu_f(bf2f(u.x))); u.y = f2bf(gelu_f(bf2f(u.y)));
  u.z = f2bf(gelu_f(bf2f(u.z))); u.w = f2bf(gelu_f(bf2f(u.w)));
  ((ushort4*)x)[i] = u;
}

__global__ __launch_bounds__(256) void cvt_bf_kernel(
    const float* __restrict__ src, unsigned short* __restrict__ dst, size_t n4)
{
  size_t i = ((size_t)blockIdx.x * 256 + threadIdx.x);
  if (i >= n4) return;
  float4 v = ((const float4*)src)[i];
  ushort4 o; o.x = f2bf(v.x); o.y = f2bf(v.y); o.z = f2bf(v.z); o.w = f2bf(v.w);
  ((ushort4*)dst)[i] = o;
}

// ---------------------------------------------------------------------------
// CSR build (unchanged from round 3)
// ---------------------------------------------------------------------------
__global__ __launch_bounds__(256) void count_v(const int* __restrict__ e0,
                                               int* __restrict__ degv) {
  int i = blockIdx.x * 256 + threadIdx.x;
  if (i >= EC) return;
  atomicAdd(&degv[e0[EC + i]], 1);
}
__global__ __launch_bounds__(256) void count_o(const int* __restrict__ e1,
                                               const int* __restrict__ e2,
                                               int* __restrict__ dego) {
  int i = blockIdx.x * 256 + threadIdx.x;
  if (i >= 2*EC) return;
  int dst = (i < EC) ? e1[EC + i] : e2[EC + (i - EC)];
  atomicAdd(&dego[dst], 1);
}
__global__ __launch_bounds__(1024) void scan_n(
    const int* __restrict__ deg, int* __restrict__ indptr,
    int* __restrict__ cursor, int n)
{
  __shared__ int ts[1024];
  const int tid = threadIdx.x;
  const int per = (n + 1023) / 1024;
  int s0 = tid * per, s1 = s0 + per; if (s1 > n) s1 = n; if (s0 > n) s0 = n;
  int loc = 0;
  for (int i = s0; i < s1; i++) loc += deg[i];
  ts[tid] = loc;
  __syncthreads();
  for (int off = 1; off < 1024; off <<= 1) {
    int v = (tid >= off) ? ts[tid - off] : 0;
    __syncthreads();
    ts[tid] += v;
    __syncthreads();
  }
  int base = (tid == 0) ? 0 : ts[tid - 1];
  for (int i = s0; i < s1; i++) {
    indptr[i] = base; cursor[i] = base; base += deg[i];
  }
  if (tid == 0) indptr[n] = ts[1023];
}
__global__ __launch_bounds__(256) void scat_v(const int* __restrict__ e0,
                                              int* __restrict__ cv,
                                              int* __restrict__ adjv) {
  int i = blockIdx.x * 256 + threadIdx.x;
  if (i >= EC) return;
  int pos = atomicAdd(&cv[e0[EC + i]], 1);
  adjv[pos] = e0[i];
}
__global__ __launch_bounds__(256) void scat_o(const int* __restrict__ e1,
                                              const int* __restrict__ e2,
                                              int* __restrict__ co,
                                              int* __restrict__ adjo) {
  int i = blockIdx.x * 256 + threadIdx.x;
  if (i >= 2*EC) return;
  int dst, srcg;
  if (i < EC) { dst = e1[EC + i]; srcg = NN + e1[i]; }
  else        { int j = i - EC; dst = e2[EC + j]; srcg = e2[j]; }
  int pos = atomicAdd(&co[dst], 1);
  adjo[pos] = srcg;
}

// ---------------------------------------------------------------------------
__global__ __launch_bounds__(256) void colmean_kernel(
    const float* __restrict__ gmat, double* __restrict__ outp, int n)
{
  const int c = threadIdx.x;
  const int r0 = blockIdx.x * 256;
  int rend = r0 + 256; if (rend > n) rend = n;
  double sum = 0.0;
  for (int r = r0; r < rend; r++) sum += (double)gmat[(size_t)r * FD + c];
  atomicAdd(&outp[c], sum);
}

__global__ __launch_bounds__(256) void head_kernel(
    const double* __restrict__ meand,
    const float* __restrict__ Wagg2, const float* __restrict__ bagg2,
    const float* __restrict__ Wo, const float* __restrict__ bo,
    float* __restrict__ outp)
{
  __shared__ float mv[256];
  __shared__ float h2[128];
  const int tid = threadIdx.x;
  mv[tid] = (float)(meand[tid] * (1.0 / (double)NTOT));
  __syncthreads();
  if (tid < 128) {
    float acc = bagg2[tid];
    for (int k = 0; k < 256; k++) acc = fmaf(mv[k], Wagg2[k*128 + tid], acc);
    h2[tid] = gelu_f(acc);
  }
  __syncthreads();
  if (tid < 16) {
    float acc = bo[tid];
    for (int k = 0; k < 128; k++) acc = fmaf(h2[k], Wo[k*16 + tid], acc);
    if (isnan(acc)) acc = 0.f;
    else if (isinf(acc)) acc = (acc > 0.f) ? 3.4028234663852886e38f : -3.4028234663852886e38f;
    outp[tid] = acc;
  }
}

__global__ void fill_kernel(float* p, int n, float v) {
  int i = blockIdx.x * 64 + threadIdx.x;
  if (i < n) p[i] = v;
}

// ---------------------------------------------------------------------------
extern "C" void kernel_launch(void* const* d_in, const int* in_sizes, int n_in,
                              void* d_out, int out_size, void* d_ws, size_t ws_size,
                              hipStream_t stream)
{
  const float* x_op_in  = (const float*)d_in[0];
  const float* x_var_in = (const float*)d_in[1];
  struct LayerP { const float *Wkqv,*bkqv,*Wkrel,*Wvrel,*prel,*Wout,*bout,*skip; };
  LayerP L[3];
  for (int i = 0; i < 3; i++) {
    int b = 2 + i*8;
    L[i].Wkqv  = (const float*)d_in[b+0];
    L[i].bkqv  = (const float*)d_in[b+1];
    L[i].Wkrel = (const float*)d_in[b+2];
    L[i].Wvrel = (const float*)d_in[b+3];
    L[i].prel  = (const float*)d_in[b+4];
    L[i].Wout  = (const float*)d_in[b+5];
    L[i].bout  = (const float*)d_in[b+6];
    L[i].skip  = (const float*)d_in[b+7];
  }
  const float* ln_g  = (const float*)d_in[26];
  const float* ln_b  = (const float*)d_in[27];
  const float* Wagg1 = (const float*)d_in[28];
  const float* bagg1 = (const float*)d_in[29];
  const float* Wagg2 = (const float*)d_in[30];
  const float* bagg2 = (const float*)d_in[31];
  const float* Wo    = (const float*)d_in[32];
  const float* bo    = (const float*)d_in[33];
  const int* e0 = (const int*)d_in[34];   // op -> var
  const int* e1 = (const int*)d_in[35];   // var -> op
  const int* e2 = (const int*)d_in[36];   // op -> op

  // ---- workspace layout (~241 MiB) ----
  float* base = (float*)d_ws;
  unsigned short* Xb   = (unsigned short*)base;            // [2NN,256] bf16 (NF float-slots)
  unsigned short* Xbop = Xb;
  unsigned short* Xbvar= Xb + NF;                          // ushort offset NN*256 == NF
  float* Qb            = base + NF;                        // [NN,256] f32
  unsigned short* aggb = (unsigned short*)(base + 2*NF);   // [NN,256] bf16 (NF/2 slots)
  unsigned short* KEu  = (unsigned short*)(base + 2*NF + NF/2);  // [2NN,256] bf16
  unsigned short* VEu  = (unsigned short*)(base + 3*NF + NF/2);  // [2NN,256] bf16
  float* wb            = base + 4*NF + NF/2;
  unsigned short* Bo1t = (unsigned short*)wb;              // [512,256] bf16
  unsigned short* Bvt  = Bo1t + 512*256;                   // [768,256] bf16
  unsigned short* Bo3t = Bvt + 768*256;                    // [768,256] bf16
  unsigned short* Wtt  = Bo3t + 768*256;                   // 8 x [256,256] bf16
  float* b_o1 = (float*)(Wtt + 8*65536);                   // 512
  float* b_v  = b_o1 + 512;                                // 768
  float* b_o3 = b_v + 768;                                 // 768
  double* meand = (double*)(b_o3 + 768);                   // 256 doubles
  int* ipv  = (int*)(meand + 256);
  int* ipo  = ipv + (NN + 1);
  int* cv   = ipo + (NN + 1);
  int* co   = cv + NN;
  int* degv = co + NN;
  int* dego = degv + NN;
  int* adjv = dego + NN;                                   // EC
  int* adjo = adjv + EC;                                   // 2*EC
  size_t need = (size_t)((char*)(adjo + 2*EC) - (char*)d_ws);
  if (ws_size < need) {   // sentinel encodes ws_size in MiB*1000
    float v = (float)(ws_size >> 20) * 1000.0f;
    fill_kernel<<<dim3((out_size + 63)/64), 64, 0, stream>>>((float*)d_out, out_size, v);
    return;
  }

  // ---- CSR build ----
  hipMemsetAsync(degv, 0, 2*NN*sizeof(int), stream);
  hipMemsetAsync(meand, 0, 256*sizeof(double), stream);
  count_v<<<dim3((EC + 255)/256), 256, 0, stream>>>(e0, degv);
  count_o<<<dim3((2*EC + 255)/256), 256, 0, stream>>>(e1, e2, dego);
  scan_n<<<dim3(1), 1024, 0, stream>>>(degv, ipv, cv, NN);
  scan_n<<<dim3(1), 1024, 0, stream>>>(dego, ipo, co, NN);
  scat_v<<<dim3((EC + 255)/256), 256, 0, stream>>>(e0, cv, adjv);
  scat_o<<<dim3((2*EC + 255)/256), 256, 0, stream>>>(e1, e2, co, adjo);

  // ---- one-time weight transposes (bf16) + input conversion ----
  for (int i = 0; i < 3; i++) {
    wcvt_kernel<<<dim3(256), 256, 0, stream>>>(L[i].Wout,         Wtt + (size_t)(i*2)  *65536);
    wcvt_kernel<<<dim3(256), 256, 0, stream>>>(L[i].Wout + 65536, Wtt + (size_t)(i*2+1)*65536);
  }
  wcvt_kernel<<<dim3(256), 256, 0, stream>>>(Wagg1,         Wtt + (size_t)6*65536);
  wcvt_kernel<<<dim3(256), 256, 0, stream>>>(Wagg1 + 65536, Wtt + (size_t)7*65536);
  cvt_bf_kernel<<<dim3((int)(NF/4 + 255)/256), 256, 0, stream>>>(x_op_in,  Xbop,  NF/4);
  cvt_bf_kernel<<<dim3((int)(NF/4 + 255)/256), 256, 0, stream>>>(x_var_in, Xbvar, NF/4);

  const dim3 gw6(6, 391), gw4(4, 391), gw2(2, 391);
  const dim3 ga((NN*64 + 255)/256);

  for (int layer = 0; layer < 3; layer++) {
    const LayerP& P = L[layer];
    const unsigned short* Wo_op  = Wtt + (size_t)(layer*2)  *65536;
    const unsigned short* Wo_var = Wtt + (size_t)(layer*2+1)*65536;

    wcomb_kernel<<<dim3(6, 8), 256, 0, stream>>>(P.Wkqv, P.bkqv, P.Wkrel, P.Wvrel,
                                                 P.prel, Bo1t, Bvt, Bo3t, b_o1, b_v, b_o3);
    qpack_kernel<<<dim3(256, 2), 256, 0, stream>>>(P.Wkqv, P.bkqv, Bo3t, Bvt, b_o3, b_v);

    // ---- VAR-dst phase (et0: op -> var) ----
    gemm_bf<3,0><<<gw4, 256, 0, stream>>>(              // [KE0|VE0] rows [0,NN)
        Xbop, Bo1t, b_o1, KEu, VEu, nullptr, nullptr, nullptr, NN);
    gemm_bf<0,0><<<gw6, 256, 0, stream>>>(              // [Q_var|KE1|VE1]
        Xbvar, Bvt, b_v, Qb, KEu + NF, VEu + NF, nullptr, nullptr, NN);
    attn_union<<<ga, 256, 0, stream>>>(Qb, KEu, VEu, ipv, adjv, aggb);
    if (layer == 0)
      gemm_bf<1,0><<<gw2, 256, 0, stream>>>(aggb, Wo_var, P.bout + 256,
          Xbvar, nullptr, nullptr, x_var_in, P.skip + 1, NN);
    else
      gemm_bf<1,1><<<gw2, 256, 0, stream>>>(aggb, Wo_var, P.bout + 256,
          Xbvar, nullptr, nullptr, Xbvar, P.skip + 1, NN);

    // ---- OP-dst phase (et1: var->op rows [NN,2NN); et2: op->op rows [0,NN)) ----
    gemm_bf<0,0><<<gw6, 256, 0, stream>>>(              // [Q_op|KE2|VE2]
        Xbop, Bo3t, b_o3, Qb, KEu, VEu, nullptr, nullptr, NN);
    attn_union<<<ga, 256, 0, stream>>>(Qb, KEu, VEu, ipo, adjo, aggb);
    if (layer == 0)
      gemm_bf<1,0><<<gw2, 256, 0, stream>>>(aggb, Wo_op, P.bout,
          Xbop, nullptr, nullptr, x_op_in, P.skip, NN);
    else
      gemm_bf<1,1><<<gw2, 256, 0, stream>>>(aggb, Wo_op, P.bout,
          Xbop, nullptr, nullptr, Xbop, P.skip, NN);

    // ---- inter-layer elementwise on Xb (bf16, in f32 math) ----
    if (layer == 0)
      ln_gelu_kernel<<<dim3((NTOT*64 + 255)/256), 256, 0, stream>>>(Xb, ln_g, ln_b);
    else
      gelu_bf_kernel<<<dim3((int)(2*NF/4 + 255)/256), 256, 0, stream>>>(Xb, 2*NF/4);
  }

  // ---- final head: gelu(X @ Wagg1 + b) -> f64 column mean -> f32 MLP ----
  gemm_bf<2,0><<<gw2, 256, 0, stream>>>(Xbop, Wtt + (size_t)6*65536, bagg1,
      Qb, nullptr, nullptr, nullptr, nullptr, NN);
  colmean_kernel<<<dim3((NN + 255)/256), 256, 0, stream>>>(Qb, meand, NN);
  gemm_bf<2,0><<<gw2, 256, 0, stream>>>(Xbvar, Wtt + (size_t)7*65536, bagg1 + 256,
      Qb, nullptr, nullptr, nullptr, nullptr, NN);
  colmean_kernel<<<dim3((NN + 255)/256), 256, 0, stream>>>(Qb, meand, NN);
  head_kernel<<<dim3(1), 256, 0, stream>>>(meand, Wagg2, bagg2, Wo, bo, (float*)d_out);
}

// Round 6
// 2097.310 us; speedup vs baseline: 2.3615x; 1.0986x over previous
//
#include <hip/hip_runtime.h>
#include <math.h>

#define NN   50000      // nodes per type
#define NTOT 100000
#define FD   256        // hidden dim
#define EC   150000     // edges per edge type
#define NCH  98         // scan chunks: ceil(NN/512)

static const size_t NF = (size_t)NN * FD;   // 12.8M (= NN*256)

typedef __attribute__((ext_vector_type(8))) short bf16x8;
typedef __attribute__((ext_vector_type(4))) float f32x4;

__device__ __forceinline__ float gelu_f(float x) {
  return 0.5f * x * (1.0f + erff(x * 0.7071067811865475f));
}
__device__ __forceinline__ unsigned short f2bf(float x) {   // RTN f32->bf16
  unsigned u = __float_as_uint(x);
  u += 0x7FFFu + ((u >> 16) & 1u);
  return (unsigned short)(u >> 16);
}
__device__ __forceinline__ float bf2f(unsigned short u) {
  return __uint_as_float((unsigned)u << 16);
}

// ---------------------------------------------------------------------------
// bf16 MFMA GEMM. A: [M,256] bf16 row-major. Bt: [N,256] bf16 (W^T).
// C = A@B + bias, f32 accum. 128x128 tile, BK=64, 4 waves x (64x64).
// LDS granule-swizzled (g ^= row&7) -> conflict-free-ish ds_read_b128.
// MODE 0: multiseg N=768: seg0->d0 f32, seg1->d1 bf16, seg2->d2 bf16
// MODE 3: multiseg N=512: seg0->d0 bf16, seg1->d1 bf16
// MODE 1: N=256, skip epilogue: out bf16 d0 (in-place over Xs ok);
//         Xs f32 (XSF=0) or bf16 (XSF=1)
// MODE 2: N=256, gelu epilogue -> f32 d0
// ---------------------------------------------------------------------------
template<int MODE, int XSF>
__global__ __launch_bounds__(256) void gemm_bf(
    const unsigned short* __restrict__ A,
    const unsigned short* __restrict__ Bt,
    const float* __restrict__ bias,
    void* d0, void* d1, void* d2,
    const void* Xs, const float* __restrict__ skipp, int M)
{
  __shared__ unsigned short As[128 * 64];
  __shared__ unsigned short Bs[128 * 64];
  const int tid = threadIdx.x;
  const int lane = tid & 63;
  const int wave = tid >> 6;
  const int wr = wave >> 1, wc = wave & 1;
  const int l15 = lane & 15, lq = lane >> 4;
  const int bm = blockIdx.y * 128, bn = blockIdx.x * 128;
  // staging: thread covers granules (sr, sg0..sg0+3); granule = 8 bf16 = 16B
  const int sr = tid >> 1, sg0 = (tid & 1) * 4;
  const bool av = (bm + sr) < M;
  const unsigned short* ag = A  + (size_t)(bm + sr) * 256 + sg0 * 8;
  const unsigned short* bg = Bt + (size_t)(bn + sr) * 256 + sg0 * 8;

  f32x4 acc[4][4] = {};
  uint4 ra[4], rb[4];

#define LOADT(KT) { \
    const unsigned short* ap = ag + (KT) * 64; \
    const unsigned short* bp = bg + (KT) * 64; \
    if (av) { ra[0] = *(const uint4*)(ap);      ra[1] = *(const uint4*)(ap + 8); \
              ra[2] = *(const uint4*)(ap + 16); ra[3] = *(const uint4*)(ap + 24); } \
    else    { ra[0] = ra[1] = ra[2] = ra[3] = make_uint4(0,0,0,0); } \
    rb[0] = *(const uint4*)(bp);      rb[1] = *(const uint4*)(bp + 8); \
    rb[2] = *(const uint4*)(bp + 16); rb[3] = *(const uint4*)(bp + 24); }

  LOADT(0);
  for (int kt = 0; kt < 4; kt++) {
    __syncthreads();
    #pragma unroll
    for (int i = 0; i < 4; i++) {
      const int g = sg0 + i;
      *(uint4*)&As[sr * 64 + ((g ^ (sr & 7)) << 3)] = ra[i];
      *(uint4*)&Bs[sr * 64 + ((g ^ (sr & 7)) << 3)] = rb[i];
    }
    __syncthreads();
    if (kt < 3) LOADT(kt + 1);          // issue next-tile loads early (T14)
    #pragma unroll
    for (int ks = 0; ks < 2; ks++) {
      bf16x8 af[4], bv[4];
      const int g = ks * 4 + lq;
      #pragma unroll
      for (int mi = 0; mi < 4; mi++) {
        const int r = wr * 64 + mi * 16 + l15;
        af[mi] = *(const bf16x8*)&As[r * 64 + ((g ^ (r & 7)) << 3)];
      }
      #pragma unroll
      for (int ni = 0; ni < 4; ni++) {
        const int c = wc * 64 + ni * 16 + l15;
        bv[ni] = *(const bf16x8*)&Bs[c * 64 + ((g ^ (c & 7)) << 3)];
      }
      #pragma unroll
      for (int mi = 0; mi < 4; mi++)
        #pragma unroll
        for (int ni = 0; ni < 4; ni++)
          acc[mi][ni] = __builtin_amdgcn_mfma_f32_16x16x32_bf16(
              af[mi], bv[ni], acc[mi][ni], 0, 0, 0);
    }
  }
#undef LOADT

  const int seg = (MODE == 0 || MODE == 3) ? (bn >> 8) : 0;
  float sg = 0.f;
  if (MODE == 1) sg = 1.f / (1.f + expf(-skipp[0]));
  #pragma unroll
  for (int mi = 0; mi < 4; mi++) {
    #pragma unroll
    for (int ni = 0; ni < 4; ni++) {
      const int cp = bn + wc * 64 + ni * 16 + l15;     // packed col (bias idx)
      const float bc_ = bias[cp];
      const int co = (MODE == 0 || MODE == 3) ? (cp & 255) : cp;
      #pragma unroll
      for (int j = 0; j < 4; j++) {
        const int r = bm + wr * 64 + mi * 16 + lq * 4 + j;
        if (r >= M) continue;
        float v = acc[mi][ni][j] + bc_;
        const size_t oidx = (size_t)r * 256 + co;
        if (MODE == 2) {
          ((float*)d0)[oidx] = gelu_f(v);
        } else if (MODE == 1) {
          const float xs = XSF ? bf2f(((const unsigned short*)Xs)[oidx])
                               : ((const float*)Xs)[oidx];
          ((unsigned short*)d0)[oidx] = f2bf(sg * v + (1.f - sg) * xs);
        } else if (MODE == 0) {
          if (seg == 0) ((float*)d0)[oidx] = v;
          else ((unsigned short*)(seg == 1 ? d1 : d2))[oidx] = f2bf(v);
        } else {  // MODE 3
          ((unsigned short*)(seg == 0 ? d0 : d1))[oidx] = f2bf(v);
        }
      }
    }
  }
}

// ---------------------------------------------------------------------------
// Combined relation weights -> TRANSPOSED bf16 packed-B matrices.
// Writes are coalesced (row = packed col, col index = tid).
// ---------------------------------------------------------------------------
__global__ __launch_bounds__(256) void wcomb_kernel(
    const float* __restrict__ Wkqv, const float* __restrict__ bkqv,
    const float* __restrict__ Wkrel, const float* __restrict__ Wvrel,
    const float* __restrict__ prel,
    unsigned short* __restrict__ Bo1t, unsigned short* __restrict__ Bvt,
    unsigned short* __restrict__ Bo3t,
    float* __restrict__ bias_o1, float* __restrict__ bias_v, float* __restrict__ bias_o3)
{
  const int z = blockIdx.x, et = z >> 1, kv = z & 1;
  const int h = blockIdx.y;
  const int st = (et == 1) ? 1 : 0;
  const int cbase = (kv ? 512 : 0) + h * 32;
  const float scale = kv ? 1.0f : (prel[et*8 + h] * 0.1767766952966369f);
  unsigned short* Bdst; int ofs; float* bdst;
  if (z == 0)      { Bdst = Bo1t; ofs = 0;   bdst = bias_o1; }
  else if (z == 1) { Bdst = Bo1t; ofs = 256; bdst = bias_o1; }
  else if (z == 2) { Bdst = Bvt;  ofs = 256; bdst = bias_v;  }
  else if (z == 3) { Bdst = Bvt;  ofs = 512; bdst = bias_v;  }
  else if (z == 4) { Bdst = Bo3t; ofs = 256; bdst = bias_o3; }
  else             { Bdst = Bo3t; ofs = 512; bdst = bias_o3; }
  __shared__ float Wr[32][32];
  const int tid = threadIdx.x;
  {
    const float* wr = (kv ? Wvrel : Wkrel) + ((size_t)(h*3 + et)) * 1024;
    for (int i = tid; i < 1024; i += 256) Wr[i >> 5][i & 31] = wr[i];
  }
  __syncthreads();
  const float* w1 = Wkqv + (size_t)st * 196608 + (size_t)tid * 768 + cbase;
  float acc[32] = {};
  for (int d = 0; d < 32; d++) {
    float v = w1[d];
    #pragma unroll
    for (int j = 0; j < 32; j++) acc[j] = fmaf(v, Wr[d][j], acc[j]);
  }
  for (int j = 0; j < 32; j++)
    Bdst[(size_t)(ofs + h * 32 + j) * 256 + tid] = f2bf(acc[j] * scale);
  if (tid < 32) {
    const float* bk = bkqv + st * 768 + cbase;
    float a = 0.f;
    for (int d = 0; d < 32; d++) a = fmaf(bk[d], Wr[d][tid], a);
    bdst[ofs + h * 32 + tid] = a * scale;
  }
}

// Q weights -> transposed bf16 seg0 of Bvt / Bo3t via 32x32 LDS tile.
// grid (64, 2), block 256 (32x8).
__global__ __launch_bounds__(256) void qpack_kernel(
    const float* __restrict__ Wkqv, const float* __restrict__ bkqv,
    unsigned short* __restrict__ Bo3t, unsigned short* __restrict__ Bvt,
    float* __restrict__ bias_o3, float* __restrict__ bias_v)
{
  const int t = blockIdx.y;
  const int bx = blockIdx.x & 7, by = blockIdx.x >> 3;
  const int tx = threadIdx.x & 31, ty = threadIdx.x >> 5;
  __shared__ float tile[32][33];
  #pragma unroll
  for (int k = 0; k < 4; k++) {
    int r = by*32 + ty + 8*k, c = bx*32 + tx;
    tile[ty + 8*k][tx] = Wkqv[(size_t)t*196608 + (size_t)r*768 + 256 + c];
  }
  __syncthreads();
  unsigned short* dst = t ? Bvt : Bo3t;
  #pragma unroll
  for (int k = 0; k < 4; k++) {
    int c = bx*32 + ty + 8*k, r = by*32 + tx;
    dst[(size_t)c*256 + r] = f2bf(tile[tx][ty + 8*k]);
  }
  if (blockIdx.x == 0) {
    (t ? bias_v : bias_o3)[threadIdx.x] = bkqv[t*768 + 256 + threadIdx.x];
  }
}

// [256,256] f32 -> transposed bf16 via 32x32 LDS tile. grid 64, block 256.
__global__ __launch_bounds__(256) void wcvt_kernel(
    const float* __restrict__ src, unsigned short* __restrict__ dst)
{
  const int bx = blockIdx.x & 7, by = blockIdx.x >> 3;
  const int tx = threadIdx.x & 31, ty = threadIdx.x >> 5;
  __shared__ float tile[32][33];
  #pragma unroll
  for (int k = 0; k < 4; k++)
    tile[ty + 8*k][tx] = src[(size_t)(by*32 + ty + 8*k)*256 + bx*32 + tx];
  __syncthreads();
  #pragma unroll
  for (int k = 0; k < 4; k++)
    dst[(size_t)(bx*32 + ty + 8*k)*256 + by*32 + tx] = f2bf(tile[tx][ty + 8*k]);
}

// ---------------------------------------------------------------------------
// Union-CSR attention: one wave per dst node, online softmax over all
// in-edges; epilogue applies gelu and writes bf16 aggb.
// ---------------------------------------------------------------------------
__global__ __launch_bounds__(256) void attn_union(
    const float* __restrict__ qb,                 // [NN,256] f32
    const unsigned short* __restrict__ KEu,       // [2NN,256] bf16
    const unsigned short* __restrict__ VEu,       // [2NN,256] bf16
    const int* __restrict__ indptr, const int* __restrict__ adj,
    unsigned short* __restrict__ aggb)            // [NN,256] bf16, gelu'd
{
  const int wid = (int)(((size_t)blockIdx.x * 256 + threadIdx.x) >> 6);
  if (wid >= NN) return;
  const int lane = threadIdx.x & 63;
  const int off = lane * 4;
  const float4 q4 = *(const float4*)(qb + (size_t)wid * FD + off);
  float m = -INFINITY, s = 0.f, ax = 0.f, ay = 0.f, az = 0.f, aw = 0.f;
  const int beg = indptr[wid], end = indptr[wid + 1];
  for (int i = beg; i < end; i++) {
    const int src = adj[i];     // global src id in [0, 2*NN)
    ushort4 ku = *(const ushort4*)(KEu + (size_t)src * FD + off);
    float d = q4.x*bf2f(ku.x) + q4.y*bf2f(ku.y) + q4.z*bf2f(ku.z) + q4.w*bf2f(ku.w);
    d += __shfl_xor(d, 1); d += __shfl_xor(d, 2); d += __shfl_xor(d, 4);
    float mn = fmaxf(m, d);
    float sc = expf(m - mn);    // m=-inf on first edge -> 0
    float w  = expf(d - mn);
    s = s * sc + w;
    ushort4 vu = *(const ushort4*)(VEu + (size_t)src * FD + off);
    ax = ax*sc + w*bf2f(vu.x); ay = ay*sc + w*bf2f(vu.y);
    az = az*sc + w*bf2f(vu.z); aw = aw*sc + w*bf2f(vu.w);
    m = mn;
  }
  const float inv = 1.f / (s + 1e-16f);
  ushort4 o;
  o.x = f2bf(gelu_f(ax * inv)); o.y = f2bf(gelu_f(ay * inv));
  o.z = f2bf(gelu_f(az * inv)); o.w = f2bf(gelu_f(aw * inv));
  *(ushort4*)(aggb + (size_t)wid * FD + off) = o;
}

// ---------------------------------------------------------------------------
__global__ __launch_bounds__(256) void ln_gelu_kernel(
    unsigned short* __restrict__ x, const float* __restrict__ g,
    const float* __restrict__ b)
{
  const int wid = (int)(((size_t)blockIdx.x * 256 + threadIdx.x) >> 6);
  if (wid >= NTOT) return;
  const int lane = threadIdx.x & 63;
  const int t = (wid >= NN) ? 1 : 0;   // rows [0,NN)=op, [NN,2NN)=var
  ushort4 u = *(ushort4*)(x + (size_t)wid * FD + lane*4);
  float vx = bf2f(u.x), vy = bf2f(u.y), vz = bf2f(u.z), vw = bf2f(u.w);
  float sum = vx + vy + vz + vw;
  #pragma unroll
  for (int o = 1; o < 64; o <<= 1) sum += __shfl_xor(sum, o);
  float mu = sum * (1.f/256.f);
  float dx = vx-mu, dy = vy-mu, dz = vz-mu, dw = vw-mu;
  float vs = dx*dx + dy*dy + dz*dz + dw*dw;
  #pragma unroll
  for (int o = 1; o < 64; o <<= 1) vs += __shfl_xor(vs, o);
  float var = vs * (1.f/256.f);
  float rs = 1.f / sqrtf(var + 1e-5f);
  int c = lane*4;
  float4 gv = *(const float4*)(g + t*FD + c);
  float4 bv = *(const float4*)(b + t*FD + c);
  ushort4 o4;
  o4.x = f2bf(gelu_f(dx*rs*gv.x + bv.x));
  o4.y = f2bf(gelu_f(dy*rs*gv.y + bv.y));
  o4.z = f2bf(gelu_f(dz*rs*gv.z + bv.z));
  o4.w = f2bf(gelu_f(dw*rs*gv.w + bv.w));
  *(ushort4*)(x + (size_t)wid * FD + c) = o4;
}

__global__ __launch_bounds__(256) void gelu_bf_kernel(
    unsigned short* __restrict__ x, size_t n4)
{
  size_t i = ((size_t)blockIdx.x * 256 + threadIdx.x);
  if (i >= n4) return;
  ushort4 u = ((ushort4*)x)[i];
  u.x = f2bf(gelu_f(bf2f(u.x))); u.y = f2bf(gelu_f(bf2f(u.y)));
  u.z = f2bf(gelu_f(bf2f(u.z))); u.w = f2bf(gelu_f(bf2f(u.w)));
  ((ushort4*)x)[i] = u;
}

__global__ __launch_bounds__(256) void cvt_bf_kernel(
    const float* __restrict__ src, unsigned short* __restrict__ dst, size_t n4)
{
  size_t i = ((size_t)blockIdx.x * 256 + threadIdx.x);
  if (i >= n4) return;
  float4 v = ((const float4*)src)[i];
  ushort4 o; o.x = f2bf(v.x); o.y = f2bf(v.y); o.z = f2bf(v.z); o.w = f2bf(v.w);
  ((ushort4*)dst)[i] = o;
}

// ---------------------------------------------------------------------------
// CSR build. deg layout: [2][NN] contiguous (var then op).
// ---------------------------------------------------------------------------
__global__ __launch_bounds__(256) void count_v(const int* __restrict__ e0,
                                               int* __restrict__ degv) {
  int i = blockIdx.x * 256 + threadIdx.x;
  if (i >= EC) return;
  atomicAdd(&degv[e0[EC + i]], 1);
}
__global__ __launch_bounds__(256) void count_o(const int* __restrict__ e1,
                                               const int* __restrict__ e2,
                                               int* __restrict__ dego) {
  int i = blockIdx.x * 256 + threadIdx.x;
  if (i >= 2*EC) return;
  int dst = (i < EC) ? e1[EC + i] : e2[EC + (i - EC)];
  atomicAdd(&dego[dst], 1);
}

// --- multi-block scan: part (chunk sums) -> mid (scan partials) -> fin ---
__global__ __launch_bounds__(256) void scan_part(
    const int* __restrict__ deg,      // [2*NN]
    int* __restrict__ psum)           // [2*NCH]
{
  const int arr = blockIdx.y, ch = blockIdx.x, tid = threadIdx.x;
  int i0 = ch*512 + tid, i1 = i0 + 256;
  int s = ((i0 < NN) ? deg[arr*NN + i0] : 0) + ((i1 < NN) ? deg[arr*NN + i1] : 0);
  __shared__ int red[256];
  red[tid] = s; __syncthreads();
  #pragma unroll
  for (int off = 128; off > 0; off >>= 1) {
    if (tid < off) red[tid] += red[tid + off];
    __syncthreads();
  }
  if (tid == 0) psum[arr*NCH + ch] = red[0];
}

__global__ __launch_bounds__(256) void scan_mid(int* __restrict__ psum)
{
  const int tid = threadIdx.x;
  __shared__ int buf[2*NCH];
  if (tid < 2*NCH) buf[tid] = psum[tid];
  __syncthreads();
  if (tid < 2) {           // serial exclusive scan of NCH values per array (in LDS)
    int run = 0;
    for (int i = 0; i < NCH; i++) { int t = buf[tid*NCH + i]; buf[tid*NCH + i] = run; run += t; }
  }
  __syncthreads();
  if (tid < 2*NCH) psum[tid] = buf[tid];
}

__global__ __launch_bounds__(256) void scan_fin(
    const int* __restrict__ deg, const int* __restrict__ psum,
    int* __restrict__ ipv, int* __restrict__ ipo,
    int* __restrict__ cv, int* __restrict__ co)
{
  const int arr = blockIdx.y, ch = blockIdx.x, tid = threadIdx.x;
  __shared__ int buf[512];
  __shared__ int s2[256];
  int i0 = ch*512 + 2*tid, i1 = i0 + 1;
  buf[2*tid]   = (i0 < NN) ? deg[arr*NN + i0] : 0;
  buf[2*tid+1] = (i1 < NN) ? deg[arr*NN + i1] : 0;
  __syncthreads();
  s2[tid] = buf[2*tid] + buf[2*tid+1];
  __syncthreads();
  #pragma unroll
  for (int off = 1; off < 256; off <<= 1) {      // inclusive Hillis-Steele
    int v = (tid >= off) ? s2[tid - off] : 0;
    __syncthreads();
    s2[tid] += v;
    __syncthreads();
  }
  int ex = (tid ? s2[tid - 1] : 0) + psum[arr*NCH + ch];
  int e0 = ex, e1 = ex + buf[2*tid];
  int* ip  = arr ? ipo : ipv;
  int* cur = arr ? co  : cv;
  if (i0 < NN) { ip[i0] = e0; cur[i0] = e0; }
  if (i1 < NN) { ip[i1] = e1; cur[i1] = e1; }
  if (ch == 0 && tid == 0) ip[NN] = arr ? 2*EC : EC;   // totals known statically
}

__global__ __launch_bounds__(256) void scat_v(const int* __restrict__ e0,
                                              int* __restrict__ cv,
                                              int* __restrict__ adjv) {
  int i = blockIdx.x * 256 + threadIdx.x;
  if (i >= EC) return;
  int pos = atomicAdd(&cv[e0[EC + i]], 1);
  adjv[pos] = e0[i];
}
__global__ __launch_bounds__(256) void scat_o(const int* __restrict__ e1,
                                              const int* __restrict__ e2,
                                              int* __restrict__ co,
                                              int* __restrict__ adjo) {
  int i = blockIdx.x * 256 + threadIdx.x;
  if (i >= 2*EC) return;
  int dst, srcg;
  if (i < EC) { dst = e1[EC + i]; srcg = NN + e1[i]; }
  else        { int j = i - EC; dst = e2[EC + j]; srcg = e2[j]; }
  int pos = atomicAdd(&co[dst], 1);
  adjo[pos] = srcg;
}

// ---------------------------------------------------------------------------
__global__ __launch_bounds__(256) void colmean_kernel(
    const float* __restrict__ gmat, double* __restrict__ outp, int n)
{
  const int c = threadIdx.x;
  const int r0 = blockIdx.x * 256;
  int rend = r0 + 256; if (rend > n) rend = n;
  double sum = 0.0;
  for (int r = r0; r < rend; r++) sum += (double)gmat[(size_t)r * FD + c];
  atomicAdd(&outp[c], sum);
}

__global__ __launch_bounds__(256) void head_kernel(
    const double* __restrict__ meand,
    const float* __restrict__ Wagg2, const float* __restrict__ bagg2,
    const float* __restrict__ Wo, const float* __restrict__ bo,
    float* __restrict__ outp)
{
  __shared__ float mv[256];
  __shared__ float h2[128];
  const int tid = threadIdx.x;
  mv[tid] = (float)(meand[tid] * (1.0 / (double)NTOT));
  __syncthreads();
  if (tid < 128) {
    float acc = bagg2[tid];
    for (int k = 0; k < 256; k++) acc = fmaf(mv[k], Wagg2[k*128 + tid], acc);
    h2[tid] = gelu_f(acc);
  }
  __syncthreads();
  if (tid < 16) {
    float acc = bo[tid];
    for (int k = 0; k < 128; k++) acc = fmaf(h2[k], Wo[k*16 + tid], acc);
    if (isnan(acc)) acc = 0.f;
    else if (isinf(acc)) acc = (acc > 0.f) ? 3.4028234663852886e38f : -3.4028234663852886e38f;
    outp[tid] = acc;
  }
}

__global__ void fill_kernel(float* p, int n, float v) {
  int i = blockIdx.x * 64 + threadIdx.x;
  if (i < n) p[i] = v;
}

// ---------------------------------------------------------------------------
extern "C" void kernel_launch(void* const* d_in, const int* in_sizes, int n_in,
                              void* d_out, int out_size, void* d_ws, size_t ws_size,
                              hipStream_t stream)
{
  const float* x_op_in  = (const float*)d_in[0];
  const float* x_var_in = (const float*)d_in[1];
  struct LayerP { const float *Wkqv,*bkqv,*Wkrel,*Wvrel,*prel,*Wout,*bout,*skip; };
  LayerP L[3];
  for (int i = 0; i < 3; i++) {
    int b = 2 + i*8;
    L[i].Wkqv  = (const float*)d_in[b+0];
    L[i].bkqv  = (const float*)d_in[b+1];
    L[i].Wkrel = (const float*)d_in[b+2];
    L[i].Wvrel = (const float*)d_in[b+3];
    L[i].prel  = (const float*)d_in[b+4];
    L[i].Wout  = (const float*)d_in[b+5];
    L[i].bout  = (const float*)d_in[b+6];
    L[i].skip  = (const float*)d_in[b+7];
  }
  const float* ln_g  = (const float*)d_in[26];
  const float* ln_b  = (const float*)d_in[27];
  const float* Wagg1 = (const float*)d_in[28];
  const float* bagg1 = (const float*)d_in[29];
  const float* Wagg2 = (const float*)d_in[30];
  const float* bagg2 = (const float*)d_in[31];
  const float* Wo    = (const float*)d_in[32];
  const float* bo    = (const float*)d_in[33];
  const int* e0 = (const int*)d_in[34];   // op -> var
  const int* e1 = (const int*)d_in[35];   // var -> op
  const int* e2 = (const int*)d_in[36];   // op -> op

  // ---- workspace layout (~241 MiB) ----
  float* base = (float*)d_ws;
  unsigned short* Xb   = (unsigned short*)base;            // [2NN,256] bf16
  unsigned short* Xbop = Xb;
  unsigned short* Xbvar= Xb + NF;
  float* Qb            = base + NF;                        // [NN,256] f32
  unsigned short* aggb = (unsigned short*)(base + 2*NF);   // [NN,256] bf16
  unsigned short* KEu  = (unsigned short*)(base + 2*NF + NF/2);  // [2NN,256] bf16
  unsigned short* VEu  = (unsigned short*)(base + 3*NF + NF/2);  // [2NN,256] bf16
  float* wb            = base + 4*NF + NF/2;
  unsigned short* Bo1t = (unsigned short*)wb;              // [512,256] bf16
  unsigned short* Bvt  = Bo1t + 512*256;                   // [768,256] bf16
  unsigned short* Bo3t = Bvt + 768*256;                    // [768,256] bf16
  unsigned short* Wtt  = Bo3t + 768*256;                   // 8 x [256,256] bf16
  float* b_o1 = (float*)(Wtt + 8*65536);                   // 512
  float* b_v  = b_o1 + 512;                                // 768
  float* b_o3 = b_v + 768;                                 // 768
  double* meand = (double*)(b_o3 + 768);                   // 256 doubles
  int* ipv  = (int*)(meand + 256);
  int* ipo  = ipv + (NN + 1);
  int* cv   = ipo + (NN + 1);
  int* co   = cv + NN;
  int* degv = co + NN;        // deg[2][NN] contiguous: degv then dego
  int* dego = degv + NN;
  int* adjv = dego + NN;                                   // EC
  int* adjo = adjv + EC;                                   // 2*EC
  int* psum = adjo + 2*EC;                                 // 2*NCH
  size_t need = (size_t)((char*)(psum + 2*NCH) - (char*)d_ws);
  if (ws_size < need) {   // sentinel encodes ws_size in MiB*1000
    float v = (float)(ws_size >> 20) * 1000.0f;
    fill_kernel<<<dim3((out_size + 63)/64), 64, 0, stream>>>((float*)d_out, out_size, v);
    return;
  }

  // ---- CSR build ----
  hipMemsetAsync(degv, 0, 2*NN*sizeof(int), stream);
  hipMemsetAsync(meand, 0, 256*sizeof(double), stream);
  count_v<<<dim3((EC + 255)/256), 256, 0, stream>>>(e0, degv);
  count_o<<<dim3((2*EC + 255)/256), 256, 0, stream>>>(e1, e2, dego);
  scan_part<<<dim3(NCH, 2), 256, 0, stream>>>(degv, psum);
  scan_mid<<<dim3(1), 256, 0, stream>>>(psum);
  scan_fin<<<dim3(NCH, 2), 256, 0, stream>>>(degv, psum, ipv, ipo, cv, co);
  scat_v<<<dim3((EC + 255)/256), 256, 0, stream>>>(e0, cv, adjv);
  scat_o<<<dim3((2*EC + 255)/256), 256, 0, stream>>>(e1, e2, co, adjo);

  // ---- one-time weight transposes (bf16) + input conversion ----
  for (int i = 0; i < 3; i++) {
    wcvt_kernel<<<dim3(64), 256, 0, stream>>>(L[i].Wout,         Wtt + (size_t)(i*2)  *65536);
    wcvt_kernel<<<dim3(64), 256, 0, stream>>>(L[i].Wout + 65536, Wtt + (size_t)(i*2+1)*65536);
  }
  wcvt_kernel<<<dim3(64), 256, 0, stream>>>(Wagg1,         Wtt + (size_t)6*65536);
  wcvt_kernel<<<dim3(64), 256, 0, stream>>>(Wagg1 + 65536, Wtt + (size_t)7*65536);
  cvt_bf_kernel<<<dim3((int)(NF/4 + 255)/256), 256, 0, stream>>>(x_op_in,  Xbop,  NF/4);
  cvt_bf_kernel<<<dim3((int)(NF/4 + 255)/256), 256, 0, stream>>>(x_var_in, Xbvar, NF/4);

  const dim3 gw6(6, 391), gw4(4, 391), gw2(2, 391);
  const dim3 ga((NN*64 + 255)/256);

  for (int layer = 0; layer < 3; layer++) {
    const LayerP& P = L[layer];
    const unsigned short* Wo_op  = Wtt + (size_t)(layer*2)  *65536;
    const unsigned short* Wo_var = Wtt + (size_t)(layer*2+1)*65536;

    wcomb_kernel<<<dim3(6, 8), 256, 0, stream>>>(P.Wkqv, P.bkqv, P.Wkrel, P.Wvrel,
                                                 P.prel, Bo1t, Bvt, Bo3t, b_o1, b_v, b_o3);
    qpack_kernel<<<dim3(64, 2), 256, 0, stream>>>(P.Wkqv, P.bkqv, Bo3t, Bvt, b_o3, b_v);

    // ---- VAR-dst phase (et0: op -> var) ----
    gemm_bf<3,0><<<gw4, 256, 0, stream>>>(              // [KE0|VE0] rows [0,NN)
        Xbop, Bo1t, b_o1, KEu, VEu, nullptr, nullptr, nullptr, NN);
    gemm_bf<0,0><<<gw6, 256, 0, stream>>>(              // [Q_var|KE1|VE1]
        Xbvar, Bvt, b_v, Qb, KEu + NF, VEu + NF, nullptr, nullptr, NN);
    attn_union<<<ga, 256, 0, stream>>>(Qb, KEu, VEu, ipv, adjv, aggb);
    if (layer == 0)
      gemm_bf<1,0><<<gw2, 256, 0, stream>>>(aggb, Wo_var, P.bout + 256,
          Xbvar, nullptr, nullptr, x_var_in, P.skip + 1, NN);
    else
      gemm_bf<1,1><<<gw2, 256, 0, stream>>>(aggb, Wo_var, P.bout + 256,
          Xbvar, nullptr, nullptr, Xbvar, P.skip + 1, NN);

    // ---- OP-dst phase (et1: var->op rows [NN,2NN); et2: op->op rows [0,NN)) ----
    gemm_bf<0,0><<<gw6, 256, 0, stream>>>(              // [Q_op|KE2|VE2]
        Xbop, Bo3t, b_o3, Qb, KEu, VEu, nullptr, nullptr, NN);
    attn_union<<<ga, 256, 0, stream>>>(Qb, KEu, VEu, ipo, adjo, aggb);
    if (layer == 0)
      gemm_bf<1,0><<<gw2, 256, 0, stream>>>(aggb, Wo_op, P.bout,
          Xbop, nullptr, nullptr, x_op_in, P.skip, NN);
    else
      gemm_bf<1,1><<<gw2, 256, 0, stream>>>(aggb, Wo_op, P.bout,
          Xbop, nullptr, nullptr, Xbop, P.skip, NN);

    // ---- inter-layer elementwise on Xb (bf16, f32 math) ----
    if (layer == 0)
      ln_gelu_kernel<<<dim3((NTOT*64 + 255)/256), 256, 0, stream>>>(Xb, ln_g, ln_b);
    else
      gelu_bf_kernel<<<dim3((int)(2*NF/4 + 255)/256), 256, 0, stream>>>(Xb, 2*NF/4);
  }

  // ---- final head: gelu(X @ Wagg1 + b) -> f64 column mean -> f32 MLP ----
  gemm_bf<2,0><<<gw2, 256, 0, stream>>>(Xbop, Wtt + (size_t)6*65536, bagg1,
      Qb, nullptr, nullptr, nullptr, nullptr, NN);
  colmean_kernel<<<dim3((NN + 255)/256), 256, 0, stream>>>(Qb, meand, NN);
  gemm_bf<2,0><<<gw2, 256, 0, stream>>>(Xbvar, Wtt + (size_t)7*65536, bagg1 + 256,
      Qb, nullptr, nullptr, nullptr, nullptr, NN);
  colmean_kernel<<<dim3((NN + 255)/256), 256, 0, stream>>>(Qb, meand, NN);
  head_kernel<<<dim3(1), 256, 0, stream>>>(meand, Wagg2, bagg2, Wo, bo, (float*)d_out);
}

// Round 7
// 1853.917 us; speedup vs baseline: 2.6716x; 1.1313x over previous
//
#include <hip/hip_runtime.h>
#include <math.h>

#define NN   50000      // nodes per type
#define NTOT 100000
#define FD   256        // hidden dim
#define EC   150000     // edges per edge type
#define NCH  98         // scan chunks: ceil(NN/512)

static const size_t NF = (size_t)NN * FD;   // 12.8M (= NN*256)

typedef __attribute__((ext_vector_type(8))) short bf16x8;
typedef __attribute__((ext_vector_type(4))) float f32x4;

__device__ __forceinline__ float gelu_f(float x) {
  return 0.5f * x * (1.0f + erff(x * 0.7071067811865475f));
}
__device__ __forceinline__ unsigned short f2bf(float x) {   // RTN f32->bf16
  unsigned u = __float_as_uint(x);
  u += 0x7FFFu + ((u >> 16) & 1u);
  return (unsigned short)(u >> 16);
}
__device__ __forceinline__ float bf2f(unsigned short u) {
  return __uint_as_float((unsigned)u << 16);
}

// LDS epilogue tile addressing: 128x128 ushort, 16B granules, XOR swizzle
__device__ __forceinline__ int ep_gaddr(int row, int g) {   // granule base (ushorts)
  int gs = (g & 8) | ((g ^ (row & 7)) & 7);
  return row * 128 + gs * 8;
}

// ---------------------------------------------------------------------------
// bf16 MFMA GEMM. A:[M,256] bf16, Bt:[N,256] bf16 (W^T). f32 accum.
// 128x128 tile, BK=64, 4 waves x (64x64). XCD-swizzled 1-D grid (NBN*391).
// Epilogue: stage bf16 tile in LDS (granule-swizzled), then coalesced 16B
// stores. ALL outputs bf16.
// MODE 0: N=768 multiseg -> d0,d1,d2   MODE 3: N=512 multiseg -> d0,d1
// MODE 1: N=256 skip epilogue (Xs f32 if XSF=0 else bf16; gelu after if GC)
// MODE 2: N=256 gelu epilogue
// ---------------------------------------------------------------------------
template<int MODE, int XSF, int GC, int NBN>
__global__ __launch_bounds__(256) void gemm_bf(
    const unsigned short* __restrict__ A,
    const unsigned short* __restrict__ Bt,
    const float* __restrict__ bias,
    void* d0, void* d1, void* d2,
    const void* Xs, const float* __restrict__ skipp, int M)
{
  __shared__ unsigned short SB[2 * 128 * 64];   // As | Bs, reused by epilogue
  unsigned short* As = SB;
  unsigned short* Bs = SB + 128 * 64;
  const int tid = threadIdx.x;
  const int lane = tid & 63;
  const int wave = tid >> 6;
  const int wr = wave >> 1, wc = wave & 1;
  const int l15 = lane & 15, lq = lane >> 4;
  // XCD-aware bijective swizzle (m204): XCD k owns a contiguous wg chunk
  const int nwg = NBN * 391;
  const int orig = blockIdx.x;
  const int qq = nwg >> 3, rr8 = nwg & 7;
  const int xcd = orig & 7, loc = orig >> 3;
  const int wg = (xcd < rr8 ? xcd * (qq + 1) : rr8 * (qq + 1) + (xcd - rr8) * qq) + loc;
  const int bm = (wg / NBN) * 128, bn = (wg % NBN) * 128;
  // staging: thread covers granules (sr, sg0..sg0+3); granule = 8 bf16 = 16B
  const int sr = tid >> 1, sg0 = (tid & 1) * 4;
  const bool av = (bm + sr) < M;
  const unsigned short* ag = A  + (size_t)(bm + sr) * 256 + sg0 * 8;
  const unsigned short* bg = Bt + (size_t)(bn + sr) * 256 + sg0 * 8;

  f32x4 acc[4][4] = {};
  uint4 ra[4], rb[4];

#define LOADT(KT) { \
    const unsigned short* ap = ag + (KT) * 64; \
    const unsigned short* bp = bg + (KT) * 64; \
    if (av) { ra[0] = *(const uint4*)(ap);      ra[1] = *(const uint4*)(ap + 8); \
              ra[2] = *(const uint4*)(ap + 16); ra[3] = *(const uint4*)(ap + 24); } \
    else    { ra[0] = ra[1] = ra[2] = ra[3] = make_uint4(0,0,0,0); } \
    rb[0] = *(const uint4*)(bp);      rb[1] = *(const uint4*)(bp + 8); \
    rb[2] = *(const uint4*)(bp + 16); rb[3] = *(const uint4*)(bp + 24); }

  LOADT(0);
  for (int kt = 0; kt < 4; kt++) {
    __syncthreads();
    #pragma unroll
    for (int i = 0; i < 4; i++) {
      const int g = sg0 + i;
      *(uint4*)&As[sr * 64 + ((g ^ (sr & 7)) << 3)] = ra[i];
      *(uint4*)&Bs[sr * 64 + ((g ^ (sr & 7)) << 3)] = rb[i];
    }
    __syncthreads();
    if (kt < 3) LOADT(kt + 1);          // issue next-tile loads early (T14)
    #pragma unroll
    for (int ks = 0; ks < 2; ks++) {
      bf16x8 af[4], bv[4];
      const int g = ks * 4 + lq;
      #pragma unroll
      for (int mi = 0; mi < 4; mi++) {
        const int r = wr * 64 + mi * 16 + l15;
        af[mi] = *(const bf16x8*)&As[r * 64 + ((g ^ (r & 7)) << 3)];
      }
      #pragma unroll
      for (int ni = 0; ni < 4; ni++) {
        const int c = wc * 64 + ni * 16 + l15;
        bv[ni] = *(const bf16x8*)&Bs[c * 64 + ((g ^ (c & 7)) << 3)];
      }
      #pragma unroll
      for (int mi = 0; mi < 4; mi++)
        #pragma unroll
        for (int ni = 0; ni < 4; ni++)
          acc[mi][ni] = __builtin_amdgcn_mfma_f32_16x16x32_bf16(
              af[mi], bv[ni], acc[mi][ni], 0, 0, 0);
    }
  }
#undef LOADT

  // ---- epilogue phase A: bias (+gelu for MODE2), stage bf16 tile in LDS ----
  __syncthreads();                       // all waves done reading As/Bs
  #pragma unroll
  for (int mi = 0; mi < 4; mi++) {
    #pragma unroll
    for (int ni = 0; ni < 4; ni++) {
      const int col = wc * 64 + ni * 16 + l15;
      const float bc_ = bias[bn + col];
      const int g = col >> 3;
      #pragma unroll
      for (int j = 0; j < 4; j++) {
        const int row = wr * 64 + mi * 16 + lq * 4 + j;
        float v = acc[mi][ni][j] + bc_;
        if (MODE == 2) v = gelu_f(v);
        SB[ep_gaddr(row, g) + (col & 7)] = f2bf(v);
      }
    }
  }
  __syncthreads();

  // ---- epilogue phase B: coalesced 16B stores (+skip/gelu for MODE1) ----
  const int seg = (MODE == 0 || MODE == 3) ? (bn >> 8) : 0;
  const int cb  = (MODE == 0 || MODE == 3) ? (bn & 255) : bn;
  unsigned short* dst;
  if (MODE == 0)      dst = (unsigned short*)(seg == 0 ? d0 : (seg == 1 ? d1 : d2));
  else if (MODE == 3) dst = (unsigned short*)(seg == 0 ? d0 : d1);
  else                dst = (unsigned short*)d0;
  float sg = 0.f;
  if (MODE == 1) sg = 1.f / (1.f + expf(-skipp[0]));
  const int rt = tid >> 1, half = tid & 1;
  const int r = bm + rt;
  if (r < M) {
    #pragma unroll
    for (int k = 0; k < 8; k++) {
      const int colbase = half * 64 + k * 8;
      const int g = colbase >> 3;
      uint4 w = *(const uint4*)&SB[ep_gaddr(rt, g)];
      if (MODE == 1) {
        const size_t xi = (size_t)r * 256 + cb + colbase;
        float xv[8];
        if (XSF) {
          uint4 xu = *(const uint4*)&((const unsigned short*)Xs)[xi];
          xv[0]=bf2f(xu.x&0xffff); xv[1]=bf2f(xu.x>>16);
          xv[2]=bf2f(xu.y&0xffff); xv[3]=bf2f(xu.y>>16);
          xv[4]=bf2f(xu.z&0xffff); xv[5]=bf2f(xu.z>>16);
          xv[6]=bf2f(xu.w&0xffff); xv[7]=bf2f(xu.w>>16);
        } else {
          float4 x0 = *(const float4*)&((const float*)Xs)[xi];
          float4 x1 = *(const float4*)&((const float*)Xs)[xi + 4];
          xv[0]=x0.x; xv[1]=x0.y; xv[2]=x0.z; xv[3]=x0.w;
          xv[4]=x1.x; xv[5]=x1.y; xv[6]=x1.z; xv[7]=x1.w;
        }
        unsigned e[8] = { w.x&0xffffu, w.x>>16, w.y&0xffffu, w.y>>16,
                          w.z&0xffffu, w.z>>16, w.w&0xffffu, w.w>>16 };
        unsigned short o[8];
        #pragma unroll
        for (int i = 0; i < 8; i++) {
          float v = sg * bf2f((unsigned short)e[i]) + (1.f - sg) * xv[i];
          if (GC) v = gelu_f(v);
          o[i] = f2bf(v);
        }
        w.x = o[0] | ((unsigned)o[1] << 16);
        w.y = o[2] | ((unsigned)o[3] << 16);
        w.z = o[4] | ((unsigned)o[5] << 16);
        w.w = o[6] | ((unsigned)o[7] << 16);
      }
      *(uint4*)&dst[(size_t)r * 256 + cb + colbase] = w;
    }
  }
}

// ---------------------------------------------------------------------------
// Combined relation weights -> TRANSPOSED bf16 packed-B matrices.
// ---------------------------------------------------------------------------
__global__ __launch_bounds__(256) void wcomb_kernel(
    const float* __restrict__ Wkqv, const float* __restrict__ bkqv,
    const float* __restrict__ Wkrel, const float* __restrict__ Wvrel,
    const float* __restrict__ prel,
    unsigned short* __restrict__ Bo1t, unsigned short* __restrict__ Bvt,
    unsigned short* __restrict__ Bo3t,
    float* __restrict__ bias_o1, float* __restrict__ bias_v, float* __restrict__ bias_o3)
{
  const int z = blockIdx.x, et = z >> 1, kv = z & 1;
  const int h = blockIdx.y;
  const int st = (et == 1) ? 1 : 0;
  const int cbase = (kv ? 512 : 0) + h * 32;
  const float scale = kv ? 1.0f : (prel[et*8 + h] * 0.1767766952966369f);
  unsigned short* Bdst; int ofs; float* bdst;
  if (z == 0)      { Bdst = Bo1t; ofs = 0;   bdst = bias_o1; }
  else if (z == 1) { Bdst = Bo1t; ofs = 256; bdst = bias_o1; }
  else if (z == 2) { Bdst = Bvt;  ofs = 256; bdst = bias_v;  }
  else if (z == 3) { Bdst = Bvt;  ofs = 512; bdst = bias_v;  }
  else if (z == 4) { Bdst = Bo3t; ofs = 256; bdst = bias_o3; }
  else             { Bdst = Bo3t; ofs = 512; bdst = bias_o3; }
  __shared__ float Wr[32][32];
  const int tid = threadIdx.x;
  {
    const float* wr = (kv ? Wvrel : Wkrel) + ((size_t)(h*3 + et)) * 1024;
    for (int i = tid; i < 1024; i += 256) Wr[i >> 5][i & 31] = wr[i];
  }
  __syncthreads();
  const float* w1 = Wkqv + (size_t)st * 196608 + (size_t)tid * 768 + cbase;
  float acc[32] = {};
  for (int d = 0; d < 32; d++) {
    float v = w1[d];
    #pragma unroll
    for (int j = 0; j < 32; j++) acc[j] = fmaf(v, Wr[d][j], acc[j]);
  }
  for (int j = 0; j < 32; j++)
    Bdst[(size_t)(ofs + h * 32 + j) * 256 + tid] = f2bf(acc[j] * scale);
  if (tid < 32) {
    const float* bk = bkqv + st * 768 + cbase;
    float a = 0.f;
    for (int d = 0; d < 32; d++) a = fmaf(bk[d], Wr[d][tid], a);
    bdst[ofs + h * 32 + tid] = a * scale;
  }
}

// Q weights -> transposed bf16 seg0 of Bvt / Bo3t via 32x32 LDS tile.
__global__ __launch_bounds__(256) void qpack_kernel(
    const float* __restrict__ Wkqv, const float* __restrict__ bkqv,
    unsigned short* __restrict__ Bo3t, unsigned short* __restrict__ Bvt,
    float* __restrict__ bias_o3, float* __restrict__ bias_v)
{
  const int t = blockIdx.y;
  const int bx = blockIdx.x & 7, by = blockIdx.x >> 3;
  const int tx = threadIdx.x & 31, ty = threadIdx.x >> 5;
  __shared__ float tile[32][33];
  #pragma unroll
  for (int k = 0; k < 4; k++) {
    int r = by*32 + ty + 8*k, c = bx*32 + tx;
    tile[ty + 8*k][tx] = Wkqv[(size_t)t*196608 + (size_t)r*768 + 256 + c];
  }
  __syncthreads();
  unsigned short* dst = t ? Bvt : Bo3t;
  #pragma unroll
  for (int k = 0; k < 4; k++) {
    int c = bx*32 + ty + 8*k, r = by*32 + tx;
    dst[(size_t)c*256 + r] = f2bf(tile[tx][ty + 8*k]);
  }
  if (blockIdx.x == 0) {
    (t ? bias_v : bias_o3)[threadIdx.x] = bkqv[t*768 + 256 + threadIdx.x];
  }
}

// [256,256] f32 -> transposed bf16 via 32x32 LDS tile. grid 64, block 256.
__global__ __launch_bounds__(256) void wcvt_kernel(
    const float* __restrict__ src, unsigned short* __restrict__ dst)
{
  const int bx = blockIdx.x & 7, by = blockIdx.x >> 3;
  const int tx = threadIdx.x & 31, ty = threadIdx.x >> 5;
  __shared__ float tile[32][33];
  #pragma unroll
  for (int k = 0; k < 4; k++)
    tile[ty + 8*k][tx] = src[(size_t)(by*32 + ty + 8*k)*256 + bx*32 + tx];
  __syncthreads();
  #pragma unroll
  for (int k = 0; k < 4; k++)
    dst[(size_t)(bx*32 + ty + 8*k)*256 + by*32 + tx] = f2bf(tile[tx][ty + 8*k]);
}

// ---------------------------------------------------------------------------
// Union-CSR attention: one wave per dst node, online softmax over all
// in-edges; epilogue applies gelu and writes bf16 aggb. Q is bf16.
// ---------------------------------------------------------------------------
__global__ __launch_bounds__(256) void attn_union(
    const unsigned short* __restrict__ qb,        // [NN,256] bf16
    const unsigned short* __restrict__ KEu,       // [2NN,256] bf16
    const unsigned short* __restrict__ VEu,       // [2NN,256] bf16
    const int* __restrict__ indptr, const int* __restrict__ adj,
    unsigned short* __restrict__ aggb)            // [NN,256] bf16, gelu'd
{
  const int wid = (int)(((size_t)blockIdx.x * 256 + threadIdx.x) >> 6);
  if (wid >= NN) return;
  const int lane = threadIdx.x & 63;
  const int off = lane * 4;
  ushort4 qu = *(const ushort4*)(qb + (size_t)wid * FD + off);
  const float qx = bf2f(qu.x), qy = bf2f(qu.y), qz = bf2f(qu.z), qw = bf2f(qu.w);
  float m = -INFINITY, s = 0.f, ax = 0.f, ay = 0.f, az = 0.f, aw = 0.f;
  const int beg = indptr[wid], end = indptr[wid + 1];
  for (int i = beg; i < end; i++) {
    const int src = adj[i];     // global src id in [0, 2*NN)
    ushort4 ku = *(const ushort4*)(KEu + (size_t)src * FD + off);
    float d = qx*bf2f(ku.x) + qy*bf2f(ku.y) + qz*bf2f(ku.z) + qw*bf2f(ku.w);
    d += __shfl_xor(d, 1); d += __shfl_xor(d, 2); d += __shfl_xor(d, 4);
    float mn = fmaxf(m, d);
    float sc = expf(m - mn);    // m=-inf on first edge -> 0
    float w  = expf(d - mn);
    s = s * sc + w;
    ushort4 vu = *(const ushort4*)(VEu + (size_t)src * FD + off);
    ax = ax*sc + w*bf2f(vu.x); ay = ay*sc + w*bf2f(vu.y);
    az = az*sc + w*bf2f(vu.z); aw = aw*sc + w*bf2f(vu.w);
    m = mn;
  }
  const float inv = 1.f / (s + 1e-16f);
  ushort4 o;
  o.x = f2bf(gelu_f(ax * inv)); o.y = f2bf(gelu_f(ay * inv));
  o.z = f2bf(gelu_f(az * inv)); o.w = f2bf(gelu_f(aw * inv));
  *(ushort4*)(aggb + (size_t)wid * FD + off) = o;
}

// ---------------------------------------------------------------------------
__global__ __launch_bounds__(256) void ln_gelu_kernel(
    unsigned short* __restrict__ x, const float* __restrict__ g,
    const float* __restrict__ b)
{
  const int wid = (int)(((size_t)blockIdx.x * 256 + threadIdx.x) >> 6);
  if (wid >= NTOT) return;
  const int lane = threadIdx.x & 63;
  const int t = (wid >= NN) ? 1 : 0;   // rows [0,NN)=op, [NN,2NN)=var
  ushort4 u = *(ushort4*)(x + (size_t)wid * FD + lane*4);
  float vx = bf2f(u.x), vy = bf2f(u.y), vz = bf2f(u.z), vw = bf2f(u.w);
  float sum = vx + vy + vz + vw;
  #pragma unroll
  for (int o = 1; o < 64; o <<= 1) sum += __shfl_xor(sum, o);
  float mu = sum * (1.f/256.f);
  float dx = vx-mu, dy = vy-mu, dz = vz-mu, dw = vw-mu;
  float vs = dx*dx + dy*dy + dz*dz + dw*dw;
  #pragma unroll
  for (int o = 1; o < 64; o <<= 1) vs += __shfl_xor(vs, o);
  float var = vs * (1.f/256.f);
  float rs = 1.f / sqrtf(var + 1e-5f);
  int c = lane*4;
  float4 gv = *(const float4*)(g + t*FD + c);
  float4 bv = *(const float4*)(b + t*FD + c);
  ushort4 o4;
  o4.x = f2bf(gelu_f(dx*rs*gv.x + bv.x));
  o4.y = f2bf(gelu_f(dy*rs*gv.y + bv.y));
  o4.z = f2bf(gelu_f(dz*rs*gv.z + bv.z));
  o4.w = f2bf(gelu_f(dw*rs*gv.w + bv.w));
  *(ushort4*)(x + (size_t)wid * FD + c) = o4;
}

__global__ __launch_bounds__(256) void cvt_bf_kernel(
    const float* __restrict__ src, unsigned short* __restrict__ dst, size_t n4)
{
  size_t i = ((size_t)blockIdx.x * 256 + threadIdx.x);
  if (i >= n4) return;
  float4 v = ((const float4*)src)[i];
  ushort4 o; o.x = f2bf(v.x); o.y = f2bf(v.y); o.z = f2bf(v.z); o.w = f2bf(v.w);
  ((ushort4*)dst)[i] = o;
}

// ---------------------------------------------------------------------------
// CSR build. deg layout: [2][NN] contiguous (var then op).
// ---------------------------------------------------------------------------
__global__ __launch_bounds__(256) void count_v(const int* __restrict__ e0,
                                               int* __restrict__ degv) {
  int i = blockIdx.x * 256 + threadIdx.x;
  if (i >= EC) return;
  atomicAdd(&degv[e0[EC + i]], 1);
}
__global__ __launch_bounds__(256) void count_o(const int* __restrict__ e1,
                                               const int* __restrict__ e2,
                                               int* __restrict__ dego) {
  int i = blockIdx.x * 256 + threadIdx.x;
  if (i >= 2*EC) return;
  int dst = (i < EC) ? e1[EC + i] : e2[EC + (i - EC)];
  atomicAdd(&dego[dst], 1);
}

// --- multi-block scan: part (chunk sums) -> mid (scan partials) -> fin ---
__global__ __launch_bounds__(256) void scan_part(
    const int* __restrict__ deg, int* __restrict__ psum)
{
  const int arr = blockIdx.y, ch = blockIdx.x, tid = threadIdx.x;
  int i0 = ch*512 + tid, i1 = i0 + 256;
  int s = ((i0 < NN) ? deg[arr*NN + i0] : 0) + ((i1 < NN) ? deg[arr*NN + i1] : 0);
  __shared__ int red[256];
  red[tid] = s; __syncthreads();
  #pragma unroll
  for (int off = 128; off > 0; off >>= 1) {
    if (tid < off) red[tid] += red[tid + off];
    __syncthreads();
  }
  if (tid == 0) psum[arr*NCH + ch] = red[0];
}

__global__ __launch_bounds__(256) void scan_mid(int* __restrict__ psum)
{
  const int tid = threadIdx.x;
  __shared__ int buf[2*NCH];
  if (tid < 2*NCH) buf[tid] = psum[tid];
  __syncthreads();
  if (tid < 2) {
    int run = 0;
    for (int i = 0; i < NCH; i++) { int t = buf[tid*NCH + i]; buf[tid*NCH + i] = run; run += t; }
  }
  __syncthreads();
  if (tid < 2*NCH) psum[tid] = buf[tid];
}

__global__ __launch_bounds__(256) void scan_fin(
    const int* __restrict__ deg, const int* __restrict__ psum,
    int* __restrict__ ipv, int* __restrict__ ipo,
    int* __restrict__ cv, int* __restrict__ co)
{
  const int arr = blockIdx.y, ch = blockIdx.x, tid = threadIdx.x;
  __shared__ int buf[512];
  __shared__ int s2[256];
  int i0 = ch*512 + 2*tid, i1 = i0 + 1;
  buf[2*tid]   = (i0 < NN) ? deg[arr*NN + i0] : 0;
  buf[2*tid+1] = (i1 < NN) ? deg[arr*NN + i1] : 0;
  __syncthreads();
  s2[tid] = buf[2*tid] + buf[2*tid+1];
  __syncthreads();
  #pragma unroll
  for (int off = 1; off < 256; off <<= 1) {
    int v = (tid >= off) ? s2[tid - off] : 0;
    __syncthreads();
    s2[tid] += v;
    __syncthreads();
  }
  int ex = (tid ? s2[tid - 1] : 0) + psum[arr*NCH + ch];
  int e0 = ex, e1 = ex + buf[2*tid];
  int* ip  = arr ? ipo : ipv;
  int* cur = arr ? co  : cv;
  if (i0 < NN) { ip[i0] = e0; cur[i0] = e0; }
  if (i1 < NN) { ip[i1] = e1; cur[i1] = e1; }
  if (ch == 0 && tid == 0) ip[NN] = arr ? 2*EC : EC;
}

__global__ __launch_bounds__(256) void scat_v(const int* __restrict__ e0,
                                              int* __restrict__ cv,
                                              int* __restrict__ adjv) {
  int i = blockIdx.x * 256 + threadIdx.x;
  if (i >= EC) return;
  int pos = atomicAdd(&cv[e0[EC + i]], 1);
  adjv[pos] = e0[i];
}
__global__ __launch_bounds__(256) void scat_o(const int* __restrict__ e1,
                                              const int* __restrict__ e2,
                                              int* __restrict__ co,
                                              int* __restrict__ adjo) {
  int i = blockIdx.x * 256 + threadIdx.x;
  if (i >= 2*EC) return;
  int dst, srcg;
  if (i < EC) { dst = e1[EC + i]; srcg = NN + e1[i]; }
  else        { int j = i - EC; dst = e2[EC + j]; srcg = e2[j]; }
  int pos = atomicAdd(&co[dst], 1);
  adjo[pos] = srcg;
}

// ---------------------------------------------------------------------------
__global__ __launch_bounds__(256) void colmean_kernel(
    const unsigned short* __restrict__ gmat, double* __restrict__ outp, int n)
{
  const int c = threadIdx.x;
  const int r0 = blockIdx.x * 256;
  int rend = r0 + 256; if (rend > n) rend = n;
  double sum = 0.0;
  for (int r = r0; r < rend; r++) sum += (double)bf2f(gmat[(size_t)r * FD + c]);
  atomicAdd(&outp[c], sum);
}

__global__ __launch_bounds__(256) void head_kernel(
    const double* __restrict__ meand,
    const float* __restrict__ Wagg2, const float* __restrict__ bagg2,
    const float* __restrict__ Wo, const float* __restrict__ bo,
    float* __restrict__ outp)
{
  __shared__ float mv[256];
  __shared__ float h2[128];
  const int tid = threadIdx.x;
  mv[tid] = (float)(meand[tid] * (1.0 / (double)NTOT));
  __syncthreads();
  if (tid < 128) {
    float acc = bagg2[tid];
    for (int k = 0; k < 256; k++) acc = fmaf(mv[k], Wagg2[k*128 + tid], acc);
    h2[tid] = gelu_f(acc);
  }
  __syncthreads();
  if (tid < 16) {
    float acc = bo[tid];
    for (int k = 0; k < 128; k++) acc = fmaf(h2[k], Wo[k*16 + tid], acc);
    if (isnan(acc)) acc = 0.f;
    else if (isinf(acc)) acc = (acc > 0.f) ? 3.4028234663852886e38f : -3.4028234663852886e38f;
    outp[tid] = acc;
  }
}

__global__ void fill_kernel(float* p, int n, float v) {
  int i = blockIdx.x * 64 + threadIdx.x;
  if (i < n) p[i] = v;
}

// ---------------------------------------------------------------------------
extern "C" void kernel_launch(void* const* d_in, const int* in_sizes, int n_in,
                              void* d_out, int out_size, void* d_ws, size_t ws_size,
                              hipStream_t stream)
{
  const float* x_op_in  = (const float*)d_in[0];
  const float* x_var_in = (const float*)d_in[1];
  struct LayerP { const float *Wkqv,*bkqv,*Wkrel,*Wvrel,*prel,*Wout,*bout,*skip; };
  LayerP L[3];
  for (int i = 0; i < 3; i++) {
    int b = 2 + i*8;
    L[i].Wkqv  = (const float*)d_in[b+0];
    L[i].bkqv  = (const float*)d_in[b+1];
    L[i].Wkrel = (const float*)d_in[b+2];
    L[i].Wvrel = (const float*)d_in[b+3];
    L[i].prel  = (const float*)d_in[b+4];
    L[i].Wout  = (const float*)d_in[b+5];
    L[i].bout  = (const float*)d_in[b+6];
    L[i].skip  = (const float*)d_in[b+7];
  }
  const float* ln_g  = (const float*)d_in[26];
  const float* ln_b  = (const float*)d_in[27];
  const float* Wagg1 = (const float*)d_in[28];
  const float* bagg1 = (const float*)d_in[29];
  const float* Wagg2 = (const float*)d_in[30];
  const float* bagg2 = (const float*)d_in[31];
  const float* Wo    = (const float*)d_in[32];
  const float* bo    = (const float*)d_in[33];
  const int* e0 = (const int*)d_in[34];   // op -> var
  const int* e1 = (const int*)d_in[35];   // var -> op
  const int* e2 = (const int*)d_in[36];   // op -> op

  // ---- workspace layout (~241 MiB) ----
  float* base = (float*)d_ws;
  unsigned short* Xb   = (unsigned short*)base;            // [2NN,256] bf16
  unsigned short* Xbop = Xb;
  unsigned short* Xbvar= Xb + NF;
  unsigned short* Qbf  = (unsigned short*)(base + NF);     // [NN,256] bf16 (Q / head tmp)
  unsigned short* aggb = (unsigned short*)(base + 2*NF);   // [NN,256] bf16
  unsigned short* KEu  = (unsigned short*)(base + 2*NF + NF/2);  // [2NN,256] bf16
  unsigned short* VEu  = (unsigned short*)(base + 3*NF + NF/2);  // [2NN,256] bf16
  float* wb            = base + 4*NF + NF/2;
  unsigned short* Bo1t = (unsigned short*)wb;              // [512,256] bf16
  unsigned short* Bvt  = Bo1t + 512*256;                   // [768,256] bf16
  unsigned short* Bo3t = Bvt + 768*256;                    // [768,256] bf16
  unsigned short* Wtt  = Bo3t + 768*256;                   // 8 x [256,256] bf16
  float* b_o1 = (float*)(Wtt + 8*65536);                   // 512
  float* b_v  = b_o1 + 512;                                // 768
  float* b_o3 = b_v + 768;                                 // 768
  double* meand = (double*)(b_o3 + 768);                   // 256 doubles
  int* ipv  = (int*)(meand + 256);
  int* ipo  = ipv + (NN + 1);
  int* cv   = ipo + (NN + 1);
  int* co   = cv + NN;
  int* degv = co + NN;        // deg[2][NN] contiguous
  int* dego = degv + NN;
  int* adjv = dego + NN;                                   // EC
  int* adjo = adjv + EC;                                   // 2*EC
  int* psum = adjo + 2*EC;                                 // 2*NCH
  size_t need = (size_t)((char*)(psum + 2*NCH) - (char*)d_ws);
  if (ws_size < need) {   // sentinel encodes ws_size in MiB*1000
    float v = (float)(ws_size >> 20) * 1000.0f;
    fill_kernel<<<dim3((out_size + 63)/64), 64, 0, stream>>>((float*)d_out, out_size, v);
    return;
  }

  // ---- CSR build ----
  hipMemsetAsync(degv, 0, 2*NN*sizeof(int), stream);
  hipMemsetAsync(meand, 0, 256*sizeof(double), stream);
  count_v<<<dim3((EC + 255)/256), 256, 0, stream>>>(e0, degv);
  count_o<<<dim3((2*EC + 255)/256), 256, 0, stream>>>(e1, e2, dego);
  scan_part<<<dim3(NCH, 2), 256, 0, stream>>>(degv, psum);
  scan_mid<<<dim3(1), 256, 0, stream>>>(psum);
  scan_fin<<<dim3(NCH, 2), 256, 0, stream>>>(degv, psum, ipv, ipo, cv, co);
  scat_v<<<dim3((EC + 255)/256), 256, 0, stream>>>(e0, cv, adjv);
  scat_o<<<dim3((2*EC + 255)/256), 256, 0, stream>>>(e1, e2, co, adjo);

  // ---- one-time weight transposes (bf16) + input conversion ----
  for (int i = 0; i < 3; i++) {
    wcvt_kernel<<<dim3(64), 256, 0, stream>>>(L[i].Wout,         Wtt + (size_t)(i*2)  *65536);
    wcvt_kernel<<<dim3(64), 256, 0, stream>>>(L[i].Wout + 65536, Wtt + (size_t)(i*2+1)*65536);
  }
  wcvt_kernel<<<dim3(64), 256, 0, stream>>>(Wagg1,         Wtt + (size_t)6*65536);
  wcvt_kernel<<<dim3(64), 256, 0, stream>>>(Wagg1 + 65536, Wtt + (size_t)7*65536);
  cvt_bf_kernel<<<dim3((int)(NF/4 + 255)/256), 256, 0, stream>>>(x_op_in,  Xbop,  NF/4);
  cvt_bf_kernel<<<dim3((int)(NF/4 + 255)/256), 256, 0, stream>>>(x_var_in, Xbvar, NF/4);

  const dim3 gw6(6*391), gw4(4*391), gw2(2*391);
  const dim3 ga((NN*64 + 255)/256);

  for (int layer = 0; layer < 3; layer++) {
    const LayerP& P = L[layer];
    const unsigned short* Wo_op  = Wtt + (size_t)(layer*2)  *65536;
    const unsigned short* Wo_var = Wtt + (size_t)(layer*2+1)*65536;

    wcomb_kernel<<<dim3(6, 8), 256, 0, stream>>>(P.Wkqv, P.bkqv, P.Wkrel, P.Wvrel,
                                                 P.prel, Bo1t, Bvt, Bo3t, b_o1, b_v, b_o3);
    qpack_kernel<<<dim3(64, 2), 256, 0, stream>>>(P.Wkqv, P.bkqv, Bo3t, Bvt, b_o3, b_v);

    // ---- VAR-dst phase (et0: op -> var) ----
    gemm_bf<3,0,0,4><<<gw4, 256, 0, stream>>>(          // [KE0|VE0] rows [0,NN)
        Xbop, Bo1t, b_o1, KEu, VEu, nullptr, nullptr, nullptr, NN);
    gemm_bf<0,0,0,6><<<gw6, 256, 0, stream>>>(          // [Q_var|KE1|VE1]
        Xbvar, Bvt, b_v, Qbf, KEu + NF, VEu + NF, nullptr, nullptr, NN);
    attn_union<<<ga, 256, 0, stream>>>(Qbf, KEu, VEu, ipv, adjv, aggb);
    if (layer == 0)
      gemm_bf<1,0,0,2><<<gw2, 256, 0, stream>>>(aggb, Wo_var, P.bout + 256,
          Xbvar, nullptr, nullptr, x_var_in, P.skip + 1, NN);
    else
      gemm_bf<1,1,1,2><<<gw2, 256, 0, stream>>>(aggb, Wo_var, P.bout + 256,
          Xbvar, nullptr, nullptr, Xbvar, P.skip + 1, NN);

    // ---- OP-dst phase (et1: var->op rows [NN,2NN); et2: op->op rows [0,NN)) ----
    gemm_bf<0,0,0,6><<<gw6, 256, 0, stream>>>(          // [Q_op|KE2|VE2]
        Xbop, Bo3t, b_o3, Qbf, KEu, VEu, nullptr, nullptr, NN);
    attn_union<<<ga, 256, 0, stream>>>(Qbf, KEu, VEu, ipo, adjo, aggb);
    if (layer == 0)
      gemm_bf<1,0,0,2><<<gw2, 256, 0, stream>>>(aggb, Wo_op, P.bout,
          Xbop, nullptr, nullptr, x_op_in, P.skip, NN);
    else
      gemm_bf<1,1,1,2><<<gw2, 256, 0, stream>>>(aggb, Wo_op, P.bout,
          Xbop, nullptr, nullptr, Xbop, P.skip, NN);

    // ---- inter-layer elementwise: layer0 LN+gelu; layers 1/2 gelu fused above
    if (layer == 0)
      ln_gelu_kernel<<<dim3((NTOT*64 + 255)/256), 256, 0, stream>>>(Xb, ln_g, ln_b);
  }

  // ---- final head: gelu(X @ Wagg1 + b) -> f64 column mean -> f32 MLP ----
  gemm_bf<2,0,0,2><<<gw2, 256, 0, stream>>>(Xbop, Wtt + (size_t)6*65536, bagg1,
      Qbf, nullptr, nullptr, nullptr, nullptr, NN);
  colmean_kernel<<<dim3((NN + 255)/256), 256, 0, stream>>>(Qbf, meand, NN);
  gemm_bf<2,0,0,2><<<gw2, 256, 0, stream>>>(Xbvar, Wtt + (size_t)7*65536, bagg1 + 256,
      Qbf, nullptr, nullptr, nullptr, nullptr, NN);
  colmean_kernel<<<dim3((NN + 255)/256), 256, 0, stream>>>(Qbf, meand, NN);
  head_kernel<<<dim3(1), 256, 0, stream>>>(meand, Wagg2, bagg2, Wo, bo, (float*)d_out);
}